// Round 13
// baseline (949.304 us; speedup 1.0000x reference)
//
#include <hip/hip_runtime.h>

#define N_NODES 100000
#define N_EDGES 1600000
#define NGRAPH  64
#define DIN     128
#define HID     256
#define GA      6

// bucketed CSR build
#define NBUCK  196       // ceil(100000 / 512)
#define BSHIFT 9         // 512 nodes per bucket
#define BCAP   10240     // per-bucket capacity (mean 8192, +22 sigma)

typedef __attribute__((ext_vector_type(8))) short bf16x8;
typedef __attribute__((ext_vector_type(4))) float f32x4;

__device__ __forceinline__ unsigned short f2bf(float f) {
  unsigned int u = __float_as_uint(f);
  u += 0x7fffu + ((u >> 16) & 1u);
  return (unsigned short)(u >> 16);
}
__device__ __forceinline__ float bf_lo(unsigned int u) { return __uint_as_float(u << 16); }
__device__ __forceinline__ float bf_hi(unsigned int u) { return __uint_as_float(u & 0xffff0000u); }
__device__ __forceinline__ unsigned int packbf(float lo, float hi) {
  return (unsigned int)f2bf(lo) | ((unsigned int)f2bf(hi) << 16);
}

__device__ __forceinline__ void gload16(const void* g, void* l) {
  __builtin_amdgcn_global_load_lds(
      (const __attribute__((address_space(1))) unsigned int*)g,
      (__attribute__((address_space(3))) unsigned int*)l, 16, 0, 0);
}

// ---------------- prep: all f32 -> bf16 conversions in ONE launch ----------------

__global__ __launch_bounds__(256) void cvt_all(const float* __restrict__ x,
                                               const float* __restrict__ w1a,
                                               const float* __restrict__ w1b,
                                               const float* __restrict__ w2a,
                                               const float* __restrict__ w2b,
                                               unsigned short* __restrict__ xo,
                                               unsigned short* __restrict__ o1a,
                                               unsigned short* __restrict__ o1b,
                                               unsigned short* __restrict__ o2a,
                                               unsigned short* __restrict__ o2b) {
  int bid = blockIdx.x, tid = threadIdx.x;
  if (bid < 12500) {                       // x: 12.8M elems, 4/thread
    size_t idx = ((size_t)bid * 256 + tid) * 4;
    float4 v = *(const float4*)&x[idx];
    ushort4 o;
    o.x = f2bf(v.x); o.y = f2bf(v.y); o.z = f2bf(v.z); o.w = f2bf(v.w);
    *(ushort4*)&xo[idx] = o;
    return;
  }
  bid -= 12500;
  const float* in; unsigned short* out; int shift, idx;
  if (bid < 128)      { in = w1a; out = o1a; shift = 7; idx = bid * 256 + tid; }
  else if (bid < 384) { in = w1b; out = o1b; shift = 8; idx = (bid - 128) * 256 + tid; }
  else if (bid < 640) { in = w2a; out = o2a; shift = 8; idx = (bid - 384) * 256 + tid; }
  else                { in = w2b; out = o2b; shift = 8; idx = (bid - 640) * 256 + tid; }
  int K = 1 << shift;
  int n = idx >> shift;
  int k = idx & (K - 1);
  out[idx] = f2bf(in[(size_t)k * HID + n]);
}

// ---------------- pass 1: bin edges by dst>>9 with block-local rank ----------------

__global__ __launch_bounds__(256) void bin_kernel(const int* __restrict__ esrc,
                                                  const int* __restrict__ edst,
                                                  int* __restrict__ cursor,
                                                  unsigned int* __restrict__ tmp) {
  __shared__ unsigned int pk[4096];
  __shared__ unsigned char bkb[4096];
  __shared__ int hist[NBUCK], lbase[NBUCK + 1], gbase[NBUCK], lcur[NBUCK];
  const int tid = threadIdx.x;
  const int lane = tid & 63;
  const int ebase = blockIdx.x * 4096;
  const int n = min(4096, N_EDGES - ebase);
  if (tid < NBUCK) hist[tid] = 0;
  __syncthreads();
  unsigned int pkv[16]; int bk[16];
#pragma unroll
  for (int i = 0; i < 16; i++) {
    int e = ebase + i * 256 + tid;
    bk[i] = -1;
    if (e < N_EDGES) {
      int s = esrc[e], d = edst[e];
      bk[i] = d >> BSHIFT;
      pkv[i] = (unsigned int)s | ((unsigned int)(d & ((1 << BSHIFT) - 1)) << 17);
      atomicAdd(&hist[bk[i]], 1);
    }
  }
  __syncthreads();
  if (tid < 64) {                 // 4-per-lane exclusive scan of NBUCK counts
    int i0 = 4 * tid;
    int a0 = (i0 + 0 < NBUCK) ? hist[i0 + 0] : 0;
    int a1 = (i0 + 1 < NBUCK) ? hist[i0 + 1] : 0;
    int a2 = (i0 + 2 < NBUCK) ? hist[i0 + 2] : 0;
    int a3 = (i0 + 3 < NBUCK) ? hist[i0 + 3] : 0;
    int p = a0 + a1 + a2 + a3, sc = p;
#pragma unroll
    for (int off = 1; off < 64; off <<= 1) {
      int t = __shfl_up(sc, off);
      if (lane >= off) sc += t;
    }
    int excl = sc - p;
    if (i0 + 0 < NBUCK) lbase[i0 + 0] = excl;
    if (i0 + 1 < NBUCK) lbase[i0 + 1] = excl + a0;
    if (i0 + 2 < NBUCK) lbase[i0 + 2] = excl + a0 + a1;
    if (i0 + 3 < NBUCK) lbase[i0 + 3] = excl + a0 + a1 + a2;
    if (tid == 63) lbase[NBUCK] = sc;
  }
  __syncthreads();
  if (tid < NBUCK) {
    int c = hist[tid];
    gbase[tid] = c ? atomicAdd(&cursor[tid], c) : 0;
    lcur[tid] = lbase[tid];
  }
  __syncthreads();
#pragma unroll
  for (int i = 0; i < 16; i++) {
    if (bk[i] >= 0) {
      int pos = atomicAdd(&lcur[bk[i]], 1);
      pk[pos] = pkv[i];
      bkb[pos] = (unsigned char)bk[i];
    }
  }
  __syncthreads();
#pragma unroll
  for (int i = 0; i < 16; i++) {
    int idx = i * 256 + tid;
    if (idx < n) {
      int b = bkb[idx];
      tmp[(size_t)b * BCAP + gbase[b] + (idx - lbase[b])] = pk[idx];
    }
  }
}

// ---------------- pass 2: per-bucket counting sort -> csr + ssrc ----------------

__global__ __launch_bounds__(512) void sort_kernel(const unsigned int* __restrict__ tmp,
                                                   const int* __restrict__ cnt,
                                                   int* __restrict__ csr,
                                                   int* __restrict__ ssrc) {
  __shared__ int nhist[512], ncur[512];
  __shared__ int bb[NBUCK];
  __shared__ int wsum[8];
  const int b = blockIdx.x;
  const int tid = threadIdx.x;
  const int lane = tid & 63, wid = tid >> 6;
  if (tid < 64) {                 // 4-per-lane scan of bucket counts -> edge bases
    int i0 = 4 * tid;
    int a0 = (i0 + 0 < NBUCK) ? cnt[i0 + 0] : 0;
    int a1 = (i0 + 1 < NBUCK) ? cnt[i0 + 1] : 0;
    int a2 = (i0 + 2 < NBUCK) ? cnt[i0 + 2] : 0;
    int a3 = (i0 + 3 < NBUCK) ? cnt[i0 + 3] : 0;
    int p = a0 + a1 + a2 + a3, sc = p;
#pragma unroll
    for (int off = 1; off < 64; off <<= 1) {
      int t = __shfl_up(sc, off);
      if (lane >= off) sc += t;
    }
    int excl = sc - p;
    if (i0 + 0 < NBUCK) bb[i0 + 0] = excl;
    if (i0 + 1 < NBUCK) bb[i0 + 1] = excl + a0;
    if (i0 + 2 < NBUCK) bb[i0 + 2] = excl + a0 + a1;
    if (i0 + 3 < NBUCK) bb[i0 + 3] = excl + a0 + a1 + a2;
  }
  nhist[tid] = 0;
  __syncthreads();
  const int myCnt = cnt[b];
  const int ebase = bb[b];
  const unsigned int* srcp = tmp + (size_t)b * BCAP;
  for (int i = tid; i < myCnt; i += 512)
    atomicAdd(&nhist[srcp[i] >> 17], 1);
  __syncthreads();
  // block scan of 512 node counts (1/thread, 8 waves)
  int v = nhist[tid];
  int sc = v;
#pragma unroll
  for (int off = 1; off < 64; off <<= 1) {
    int t = __shfl_up(sc, off);
    if (lane >= off) sc += t;
  }
  if (lane == 63) wsum[wid] = sc;
  __syncthreads();
  if (tid < 8) {
    int ws = wsum[tid];
#pragma unroll
    for (int off = 1; off < 8; off <<= 1) {
      int t = __shfl_up(ws, off);
      if (tid >= off) ws += t;
    }
    wsum[tid] = ws;
  }
  __syncthreads();
  int excl = ((wid > 0) ? wsum[wid - 1] : 0) + sc - v;
  ncur[tid] = excl;
  int node0 = (b << BSHIFT) + tid;
  if (node0 < N_NODES) csr[node0] = ebase + excl;
  if (b == 0 && tid == 0) csr[N_NODES] = N_EDGES;
  __syncthreads();
  for (int i = tid; i < myCnt; i += 512) {
    unsigned int pe = srcp[i];
    int pos = atomicAdd(&ncur[pe >> 17], 1);
    ssrc[ebase + pos] = (int)(pe & 0x1FFFF);
  }
}

// ---------------- aggregation (bf16 in/out, f32 accum), deep-unrolled ----------------

__global__ __launch_bounds__(256) void agg1_kernel(const uint2* __restrict__ x,
                                                   const int* __restrict__ csr,
                                                   const int* __restrict__ ssrc,
                                                   uint2* __restrict__ out) {
  int node = blockIdx.x * 4 + (threadIdx.x >> 6);
  int lane = threadIdx.x & 63;
  int half = lane >> 5;        // which edge of each pair
  int dl   = lane & 31;        // dims dl*4 .. dl*4+3
  float a0 = 0.f, a1 = 0.f, a2 = 0.f, a3 = 0.f;
  if (half == 0) {             // self term once
    uint2 u = x[(size_t)node * 32 + dl];
    a0 = bf_lo(u.x); a1 = bf_hi(u.x); a2 = bf_lo(u.y); a3 = bf_hi(u.y);
  }
  int s = csr[node], e = csr[node + 1];
  int i = s;
  for (; i + 8 <= e; i += 8) {
    int s0 = ssrc[i + half],     s1 = ssrc[i + 2 + half];
    int s2 = ssrc[i + 4 + half], s3 = ssrc[i + 6 + half];
    uint2 v0 = x[(size_t)s0 * 32 + dl];
    uint2 v1 = x[(size_t)s1 * 32 + dl];
    uint2 v2 = x[(size_t)s2 * 32 + dl];
    uint2 v3 = x[(size_t)s3 * 32 + dl];
    a0 += bf_lo(v0.x) + bf_lo(v1.x) + bf_lo(v2.x) + bf_lo(v3.x);
    a1 += bf_hi(v0.x) + bf_hi(v1.x) + bf_hi(v2.x) + bf_hi(v3.x);
    a2 += bf_lo(v0.y) + bf_lo(v1.y) + bf_lo(v2.y) + bf_lo(v3.y);
    a3 += bf_hi(v0.y) + bf_hi(v1.y) + bf_hi(v2.y) + bf_hi(v3.y);
  }
  for (; i + 2 <= e; i += 2) {
    int sn = ssrc[i + half];
    uint2 v = x[(size_t)sn * 32 + dl];
    a0 += bf_lo(v.x); a1 += bf_hi(v.x);
    a2 += bf_lo(v.y); a3 += bf_hi(v.y);
  }
  if (i < e && half == 0) {    // odd tail
    uint2 v = x[(size_t)ssrc[i] * 32 + dl];
    a0 += bf_lo(v.x); a1 += bf_hi(v.x);
    a2 += bf_lo(v.y); a3 += bf_hi(v.y);
  }
  a0 += __shfl_xor(a0, 32);
  a1 += __shfl_xor(a1, 32);
  a2 += __shfl_xor(a2, 32);
  a3 += __shfl_xor(a3, 32);
  if (half == 0) {
    uint2 o;
    o.x = packbf(a0, a1);
    o.y = packbf(a2, a3);
    out[(size_t)node * 32 + dl] = o;
  }
}

__global__ __launch_bounds__(256) void agg2_kernel(const uint2* __restrict__ x,
                                                   const int* __restrict__ csr,
                                                   const int* __restrict__ ssrc,
                                                   uint2* __restrict__ out) {
  int node = blockIdx.x * 4 + (threadIdx.x >> 6);
  int lane = threadIdx.x & 63;
  uint2 u = x[(size_t)node * 64 + lane];
  float a0 = bf_lo(u.x), a1 = bf_hi(u.x), a2 = bf_lo(u.y), a3 = bf_hi(u.y);
  int s = csr[node], e = csr[node + 1];
  int i = s;
  for (; i + 8 <= e; i += 8) {
    int n0 = ssrc[i],     n1 = ssrc[i + 1], n2 = ssrc[i + 2], n3 = ssrc[i + 3];
    int n4 = ssrc[i + 4], n5 = ssrc[i + 5], n6 = ssrc[i + 6], n7 = ssrc[i + 7];
    uint2 v0 = x[(size_t)n0 * 64 + lane];
    uint2 v1 = x[(size_t)n1 * 64 + lane];
    uint2 v2 = x[(size_t)n2 * 64 + lane];
    uint2 v3 = x[(size_t)n3 * 64 + lane];
    uint2 v4 = x[(size_t)n4 * 64 + lane];
    uint2 v5 = x[(size_t)n5 * 64 + lane];
    uint2 v6 = x[(size_t)n6 * 64 + lane];
    uint2 v7 = x[(size_t)n7 * 64 + lane];
    a0 += (bf_lo(v0.x) + bf_lo(v1.x)) + (bf_lo(v2.x) + bf_lo(v3.x)) +
          (bf_lo(v4.x) + bf_lo(v5.x)) + (bf_lo(v6.x) + bf_lo(v7.x));
    a1 += (bf_hi(v0.x) + bf_hi(v1.x)) + (bf_hi(v2.x) + bf_hi(v3.x)) +
          (bf_hi(v4.x) + bf_hi(v5.x)) + (bf_hi(v6.x) + bf_hi(v7.x));
    a2 += (bf_lo(v0.y) + bf_lo(v1.y)) + (bf_lo(v2.y) + bf_lo(v3.y)) +
          (bf_lo(v4.y) + bf_lo(v5.y)) + (bf_lo(v6.y) + bf_lo(v7.y));
    a3 += (bf_hi(v0.y) + bf_hi(v1.y)) + (bf_hi(v2.y) + bf_hi(v3.y)) +
          (bf_hi(v4.y) + bf_hi(v5.y)) + (bf_hi(v6.y) + bf_hi(v7.y));
  }
  for (; i < e; i++) {
    uint2 v = x[(size_t)ssrc[i] * 64 + lane];
    a0 += bf_lo(v.x); a1 += bf_hi(v.x);
    a2 += bf_lo(v.y); a3 += bf_hi(v.y);
  }
  uint2 o;
  o.x = packbf(a0, a1);
  o.y = packbf(a2, a3);
  out[(size_t)node * 64 + lane] = o;
}

// ---------------- GEMM: 128 rows x 256 cols per block, 8 waves, BK=64 ----------------
// Col-merged: A read ONCE from HBM (halved A traffic vs 2 col-tile blocks).
// LDS 48 KB (A 16 + W 32) -> 3 blocks/CU (launch_bounds squeezes VGPR<=85).
// 782 blocks ~= 256 CU x 3 (one near-perfect round).

template<int K, bool RELU>
__global__ __launch_bounds__(512, 6)
void gemm128(const unsigned short* __restrict__ A,
             const unsigned short* __restrict__ Wt,
             const float* __restrict__ bias,
             unsigned short* __restrict__ C) {
  __shared__ unsigned short Asl[128 * 64];   // 16 KB
  __shared__ unsigned short Wsl[256 * 64];   // 32 KB
  const int tid = threadIdx.x;
  const int lane = tid & 63;
  const int w = tid >> 6;          // 0..7
  const int wm = w >> 2;           // 0..1 (row half)
  const int wn = w & 3;            // 0..3 (col quarter)
  const int l15 = lane & 15, l4 = lane >> 4, l7 = lane & 7;
  const int rowBase = blockIdx.x * 128;

  f32x4 acc[4][4] = {};

  for (int k0 = 0; k0 < K; k0 += 64) {
#pragma unroll
    for (int i = 0; i < 2; i++) {            // stage A: 1024 chunks of 16B
      int c = i * 512 + tid;
      int m = c >> 3, koL = c & 7;
      int koS = koL ^ (m & 7);
      int gr = rowBase + m; if (gr >= N_NODES) gr = N_NODES - 1;
      gload16(&A[(size_t)gr * K + k0 + koS * 8], Asl + (size_t)c * 8);
    }
#pragma unroll
    for (int i = 0; i < 4; i++) {            // stage W: 2048 chunks of 16B
      int c = i * 512 + tid;
      int n = c >> 3, koL = c & 7;
      int koS = koL ^ (n & 7);
      gload16(&Wt[(size_t)n * K + k0 + koS * 8], Wsl + (size_t)c * 8);
    }
    __syncthreads();
#pragma unroll
    for (int kk = 0; kk < 2; kk++) {
      int koX = (kk * 4 + l4) ^ l7;
      bf16x8 a[4], b[4];
#pragma unroll
      for (int f = 0; f < 4; f++) {
        int rowA = wm * 64 + f * 16 + l15;
        int rowB = wn * 64 + f * 16 + l15;
        a[f] = *(const bf16x8*)&Asl[(size_t)(rowA * 64 + koX * 8)];
        b[f] = *(const bf16x8*)&Wsl[(size_t)(rowB * 64 + koX * 8)];
      }
#pragma unroll
      for (int fm = 0; fm < 4; fm++)
#pragma unroll
        for (int fn = 0; fn < 4; fn++)
          acc[fm][fn] = __builtin_amdgcn_mfma_f32_16x16x32_bf16(a[fm], b[fn], acc[fm][fn], 0, 0, 0);
    }
    __syncthreads();
  }

#pragma unroll
  for (int fm = 0; fm < 4; fm++) {
    int r0 = rowBase + wm * 64 + fm * 16 + l4 * 4;
#pragma unroll
    for (int fn = 0; fn < 4; fn++) {
      int col = wn * 64 + fn * 16 + l15;
      float bb = bias[col];
#pragma unroll
      for (int j = 0; j < 4; j++) {
        int r = r0 + j;
        if (r < N_NODES) {
          float v = acc[fm][fn][j] + bb;
          if (RELU) v = fmaxf(v, 0.f);
          C[(size_t)r * HID + col] = f2bf(v);
        }
      }
    }
  }
}

// ---------------- pooling ----------------

__global__ __launch_bounds__(256) void pool_kernel(const unsigned short* __restrict__ H,
                                                   const int* __restrict__ batch,
                                                   float* __restrict__ sums,
                                                   float* __restrict__ cnts) {
  int d = threadIdx.x;
  int n0 = blockIdx.x * 128;
  int n1 = n0 + 128; if (n1 > N_NODES) n1 = N_NODES;
  int cur = batch[n0];
  float run = 0.f, runc = 0.f;
  for (int i = n0; i < n1; i++) {
    int b = batch[i];
    if (b != cur) {
      atomicAdd(&sums[(size_t)cur * HID + d], run);
      if (d == 0) atomicAdd(&cnts[cur], runc);
      run = 0.f; runc = 0.f; cur = b;
    }
    run += __uint_as_float(((unsigned int)H[(size_t)i * HID + d]) << 16);
    runc += 1.f;
  }
  atomicAdd(&sums[(size_t)cur * HID + d], run);
  if (d == 0) atomicAdd(&cnts[cur], runc);
}

// ---------------- head: relu(g@wf1+bf1)@wf2+bf2, 8-deep ILP ----------------

__global__ __launch_bounds__(256) void head_kernel(const float* __restrict__ sums,
                                                   const float* __restrict__ cnts,
                                                   const float* __restrict__ gattr,
                                                   const float* __restrict__ wf1,
                                                   const float* __restrict__ bf1,
                                                   const float* __restrict__ wf2,
                                                   const float* __restrict__ bf2,
                                                   float* __restrict__ out) {
  int g = blockIdx.x, tid = threadIdx.x;
  __shared__ float gv[HID + GA + 2];   // 262 + pad
  __shared__ float red[256];
  float c = cnts[g]; c = fmaxf(c, 1.0f);
  gv[tid] = sums[(size_t)g * HID + tid] / c;
  if (tid < GA) gv[HID + tid] = gattr[g * GA + tid];
  if (tid < 2) gv[HID + GA + tid] = 0.f;
  __syncthreads();
  float ac0 = 0.f, ac1 = 0.f, ac2 = 0.f, ac3 = 0.f;
  float ac4 = 0.f, ac5 = 0.f, ac6 = 0.f, ac7 = 0.f;
  const float* wcol = wf1 + tid;
  int k = 0;
#pragma unroll 1
  for (; k + 8 <= HID + GA; k += 8) {
    float w0 = wcol[(size_t)(k + 0) * HID];
    float w1 = wcol[(size_t)(k + 1) * HID];
    float w2 = wcol[(size_t)(k + 2) * HID];
    float w3 = wcol[(size_t)(k + 3) * HID];
    float w4 = wcol[(size_t)(k + 4) * HID];
    float w5 = wcol[(size_t)(k + 5) * HID];
    float w6 = wcol[(size_t)(k + 6) * HID];
    float w7 = wcol[(size_t)(k + 7) * HID];
    ac0 = fmaf(gv[k + 0], w0, ac0);
    ac1 = fmaf(gv[k + 1], w1, ac1);
    ac2 = fmaf(gv[k + 2], w2, ac2);
    ac3 = fmaf(gv[k + 3], w3, ac3);
    ac4 = fmaf(gv[k + 4], w4, ac4);
    ac5 = fmaf(gv[k + 5], w5, ac5);
    ac6 = fmaf(gv[k + 6], w6, ac6);
    ac7 = fmaf(gv[k + 7], w7, ac7);
  }
  for (; k < HID + GA; k++)
    ac0 = fmaf(gv[k], wcol[(size_t)k * HID], ac0);
  float acc = ((ac0 + ac1) + (ac2 + ac3)) + ((ac4 + ac5) + (ac6 + ac7)) + bf1[tid];
  float h = fmaxf(acc, 0.f);
  red[tid] = h * wf2[tid];
  __syncthreads();
  for (int s = 128; s > 0; s >>= 1) {
    if (tid < s) red[tid] += red[tid + s];
    __syncthreads();
  }
  if (tid == 0) out[g] = red[0] + bf2[0];
}

// ---------------- launch ----------------

extern "C" void kernel_launch(void* const* d_in, const int* in_sizes, int n_in,
                              void* d_out, int out_size, void* d_ws, size_t ws_size,
                              hipStream_t stream) {
  const float* x     = (const float*)d_in[0];
  const int*   eidx  = (const int*)d_in[1];
  const int*   batch = (const int*)d_in[2];
  const float* gattr = (const float*)d_in[3];
  const float* w1a = (const float*)d_in[4];  const float* b1a = (const float*)d_in[5];
  const float* w1b = (const float*)d_in[6];  const float* b1b = (const float*)d_in[7];
  const float* w2a = (const float*)d_in[8];  const float* b2a = (const float*)d_in[9];
  const float* w2b = (const float*)d_in[10]; const float* b2b = (const float*)d_in[11];
  const float* wf1 = (const float*)d_in[12]; const float* bf1 = (const float*)d_in[13];
  const float* wf2 = (const float*)d_in[14]; const float* bf2 = (const float*)d_in[15];
  float* out = (float*)d_out;

  const int* esrc = eidx;
  const int* edst = eidx + N_EDGES;

  char* w = (char*)d_ws;
  auto alloc = [&](size_t bytes) -> void* {
    void* p = (void*)w;
    w += (bytes + 255) & ~(size_t)255;
    return p;
  };
  unsigned short* B0 = (unsigned short*)alloc((size_t)N_NODES * DIN * 2);  // x bf16
  unsigned short* B1 = (unsigned short*)alloc((size_t)N_NODES * HID * 2);  // agg out
  unsigned short* B2 = (unsigned short*)alloc((size_t)N_NODES * HID * 2);  // conv out
  unsigned short* B3 = (unsigned short*)alloc((size_t)N_NODES * HID * 2);  // h1
  unsigned short* w1aT = (unsigned short*)alloc(256 * 128 * 2);
  unsigned short* w1bT = (unsigned short*)alloc(256 * 256 * 2);
  unsigned short* w2aT = (unsigned short*)alloc(256 * 256 * 2);
  unsigned short* w2bT = (unsigned short*)alloc(256 * 256 * 2);
  int*   csr    = (int*)alloc((N_NODES + 4) * 4);
  int*   cursor = (int*)alloc(NBUCK * 4);
  unsigned int* tmp = (unsigned int*)alloc((size_t)NBUCK * BCAP * 4);
  int*   ssrc   = (int*)alloc((size_t)N_EDGES * 4);
  float* sums   = (float*)alloc((size_t)NGRAPH * HID * 4);
  float* cnts   = (float*)alloc(NGRAPH * 4);

  hipMemsetAsync(cursor, 0, NBUCK * 4, stream);
  hipMemsetAsync(sums, 0, (size_t)NGRAPH * HID * 4 + 256, stream);  // sums + cnts

  cvt_all<<<12500 + 896, 256, 0, stream>>>(x, w1a, w1b, w2a, w2b,
                                           B0, w1aT, w1bT, w2aT, w2bT);

  bin_kernel<<<(N_EDGES + 4095) / 4096, 256, 0, stream>>>(esrc, edst, cursor, tmp);
  sort_kernel<<<NBUCK, 512, 0, stream>>>(tmp, cursor, csr, ssrc);

  const int ngemm = (N_NODES + 127) / 128;   // 782 blocks (full 256-col tiles)

  // conv1: agg(x) -> B1[N][128]; relu(B1@W1a+b) -> B3; relu(B3@W1b+b) -> B2
  agg1_kernel<<<N_NODES / 4, 256, 0, stream>>>((const uint2*)B0, csr, ssrc, (uint2*)B1);
  gemm128<128, true><<<ngemm, 512, 0, stream>>>(B1, w1aT, b1a, B3);
  gemm128<256, true><<<ngemm, 512, 0, stream>>>(B3, w1bT, b1b, B2);
  // conv2: agg(B2) -> B1[N][256]; relu(B1@W2a+b) -> B3; B3@W2b+b -> B2
  agg2_kernel<<<N_NODES / 4, 256, 0, stream>>>((const uint2*)B2, csr, ssrc, (uint2*)B1);
  gemm128<256, true><<<ngemm, 512, 0, stream>>>(B1, w2aT, b2a, B3);
  gemm128<256, false><<<ngemm, 512, 0, stream>>>(B3, w2bT, b2b, B2);

  pool_kernel<<<(N_NODES + 127) / 128, 256, 0, stream>>>(B2, batch, sums, cnts);
  head_kernel<<<NGRAPH, 256, 0, stream>>>(sums, cnts, gattr, wf1, bf1, wf2, bf2, out);
}

// Round 14
// 411.515 us; speedup vs baseline: 2.3069x; 2.3069x over previous
//
#include <hip/hip_runtime.h>

#define N_NODES 100000
#define N_EDGES 1600000
#define NGRAPH  64
#define DIN     128
#define HID     256
#define GA      6

// bucketed CSR build
#define NBUCK  196       // ceil(100000 / 512)
#define BSHIFT 9         // 512 nodes per bucket
#define BCAP   10240     // per-bucket capacity (mean 8192, +22 sigma)

typedef __attribute__((ext_vector_type(8))) short bf16x8;
typedef __attribute__((ext_vector_type(4))) float f32x4;

__device__ __forceinline__ unsigned short f2bf(float f) {
  unsigned int u = __float_as_uint(f);
  u += 0x7fffu + ((u >> 16) & 1u);
  return (unsigned short)(u >> 16);
}
__device__ __forceinline__ float bf_lo(unsigned int u) { return __uint_as_float(u << 16); }
__device__ __forceinline__ float bf_hi(unsigned int u) { return __uint_as_float(u & 0xffff0000u); }
__device__ __forceinline__ unsigned int packbf(float lo, float hi) {
  return (unsigned int)f2bf(lo) | ((unsigned int)f2bf(hi) << 16);
}

__device__ __forceinline__ void gload16(const void* g, void* l) {
  __builtin_amdgcn_global_load_lds(
      (const __attribute__((address_space(1))) unsigned int*)g,
      (__attribute__((address_space(3))) unsigned int*)l, 16, 0, 0);
}

// ---------------- prep: all f32 -> bf16 conversions in ONE launch ----------------

__global__ __launch_bounds__(256) void cvt_all(const float* __restrict__ x,
                                               const float* __restrict__ w1a,
                                               const float* __restrict__ w1b,
                                               const float* __restrict__ w2a,
                                               const float* __restrict__ w2b,
                                               unsigned short* __restrict__ xo,
                                               unsigned short* __restrict__ o1a,
                                               unsigned short* __restrict__ o1b,
                                               unsigned short* __restrict__ o2a,
                                               unsigned short* __restrict__ o2b) {
  int bid = blockIdx.x, tid = threadIdx.x;
  if (bid < 12500) {                       // x: 12.8M elems, 4/thread
    size_t idx = ((size_t)bid * 256 + tid) * 4;
    float4 v = *(const float4*)&x[idx];
    ushort4 o;
    o.x = f2bf(v.x); o.y = f2bf(v.y); o.z = f2bf(v.z); o.w = f2bf(v.w);
    *(ushort4*)&xo[idx] = o;
    return;
  }
  bid -= 12500;
  const float* in; unsigned short* out; int shift, idx;
  if (bid < 128)      { in = w1a; out = o1a; shift = 7; idx = bid * 256 + tid; }
  else if (bid < 384) { in = w1b; out = o1b; shift = 8; idx = (bid - 128) * 256 + tid; }
  else if (bid < 640) { in = w2a; out = o2a; shift = 8; idx = (bid - 384) * 256 + tid; }
  else                { in = w2b; out = o2b; shift = 8; idx = (bid - 640) * 256 + tid; }
  int K = 1 << shift;
  int n = idx >> shift;
  int k = idx & (K - 1);
  out[idx] = f2bf(in[(size_t)k * HID + n]);
}

// ---------------- pass 1: bin edges by dst>>9 with block-local rank ----------------

__global__ __launch_bounds__(256) void bin_kernel(const int* __restrict__ esrc,
                                                  const int* __restrict__ edst,
                                                  int* __restrict__ cursor,
                                                  unsigned int* __restrict__ tmp) {
  __shared__ unsigned int pk[4096];
  __shared__ unsigned char bkb[4096];
  __shared__ int hist[NBUCK], lbase[NBUCK + 1], gbase[NBUCK], lcur[NBUCK];
  const int tid = threadIdx.x;
  const int lane = tid & 63;
  const int ebase = blockIdx.x * 4096;
  const int n = min(4096, N_EDGES - ebase);
  if (tid < NBUCK) hist[tid] = 0;
  __syncthreads();
  unsigned int pkv[16]; int bk[16];
#pragma unroll
  for (int i = 0; i < 16; i++) {
    int e = ebase + i * 256 + tid;
    bk[i] = -1;
    if (e < N_EDGES) {
      int s = esrc[e], d = edst[e];
      bk[i] = d >> BSHIFT;
      pkv[i] = (unsigned int)s | ((unsigned int)(d & ((1 << BSHIFT) - 1)) << 17);
      atomicAdd(&hist[bk[i]], 1);
    }
  }
  __syncthreads();
  if (tid < 64) {                 // 4-per-lane exclusive scan of NBUCK counts
    int i0 = 4 * tid;
    int a0 = (i0 + 0 < NBUCK) ? hist[i0 + 0] : 0;
    int a1 = (i0 + 1 < NBUCK) ? hist[i0 + 1] : 0;
    int a2 = (i0 + 2 < NBUCK) ? hist[i0 + 2] : 0;
    int a3 = (i0 + 3 < NBUCK) ? hist[i0 + 3] : 0;
    int p = a0 + a1 + a2 + a3, sc = p;
#pragma unroll
    for (int off = 1; off < 64; off <<= 1) {
      int t = __shfl_up(sc, off);
      if (lane >= off) sc += t;
    }
    int excl = sc - p;
    if (i0 + 0 < NBUCK) lbase[i0 + 0] = excl;
    if (i0 + 1 < NBUCK) lbase[i0 + 1] = excl + a0;
    if (i0 + 2 < NBUCK) lbase[i0 + 2] = excl + a0 + a1;
    if (i0 + 3 < NBUCK) lbase[i0 + 3] = excl + a0 + a1 + a2;
    if (tid == 63) lbase[NBUCK] = sc;
  }
  __syncthreads();
  if (tid < NBUCK) {
    int c = hist[tid];
    gbase[tid] = c ? atomicAdd(&cursor[tid], c) : 0;
    lcur[tid] = lbase[tid];
  }
  __syncthreads();
#pragma unroll
  for (int i = 0; i < 16; i++) {
    if (bk[i] >= 0) {
      int pos = atomicAdd(&lcur[bk[i]], 1);
      pk[pos] = pkv[i];
      bkb[pos] = (unsigned char)bk[i];
    }
  }
  __syncthreads();
#pragma unroll
  for (int i = 0; i < 16; i++) {
    int idx = i * 256 + tid;
    if (idx < n) {
      int b = bkb[idx];
      tmp[(size_t)b * BCAP + gbase[b] + (idx - lbase[b])] = pk[idx];
    }
  }
}

// ---------------- pass 2: per-bucket counting sort -> csr + ssrc ----------------

__global__ __launch_bounds__(512) void sort_kernel(const unsigned int* __restrict__ tmp,
                                                   const int* __restrict__ cnt,
                                                   int* __restrict__ csr,
                                                   int* __restrict__ ssrc) {
  __shared__ int nhist[512], ncur[512];
  __shared__ int bb[NBUCK];
  __shared__ int wsum[8];
  const int b = blockIdx.x;
  const int tid = threadIdx.x;
  const int lane = tid & 63, wid = tid >> 6;
  if (tid < 64) {                 // 4-per-lane scan of bucket counts -> edge bases
    int i0 = 4 * tid;
    int a0 = (i0 + 0 < NBUCK) ? cnt[i0 + 0] : 0;
    int a1 = (i0 + 1 < NBUCK) ? cnt[i0 + 1] : 0;
    int a2 = (i0 + 2 < NBUCK) ? cnt[i0 + 2] : 0;
    int a3 = (i0 + 3 < NBUCK) ? cnt[i0 + 3] : 0;
    int p = a0 + a1 + a2 + a3, sc = p;
#pragma unroll
    for (int off = 1; off < 64; off <<= 1) {
      int t = __shfl_up(sc, off);
      if (lane >= off) sc += t;
    }
    int excl = sc - p;
    if (i0 + 0 < NBUCK) bb[i0 + 0] = excl;
    if (i0 + 1 < NBUCK) bb[i0 + 1] = excl + a0;
    if (i0 + 2 < NBUCK) bb[i0 + 2] = excl + a0 + a1;
    if (i0 + 3 < NBUCK) bb[i0 + 3] = excl + a0 + a1 + a2;
  }
  nhist[tid] = 0;
  __syncthreads();
  const int myCnt = cnt[b];
  const int ebase = bb[b];
  const unsigned int* srcp = tmp + (size_t)b * BCAP;
  for (int i = tid; i < myCnt; i += 512)
    atomicAdd(&nhist[srcp[i] >> 17], 1);
  __syncthreads();
  // block scan of 512 node counts (1/thread, 8 waves)
  int v = nhist[tid];
  int sc = v;
#pragma unroll
  for (int off = 1; off < 64; off <<= 1) {
    int t = __shfl_up(sc, off);
    if (lane >= off) sc += t;
  }
  if (lane == 63) wsum[wid] = sc;
  __syncthreads();
  if (tid < 8) {
    int ws = wsum[tid];
#pragma unroll
    for (int off = 1; off < 8; off <<= 1) {
      int t = __shfl_up(ws, off);
      if (tid >= off) ws += t;
    }
    wsum[tid] = ws;
  }
  __syncthreads();
  int excl = ((wid > 0) ? wsum[wid - 1] : 0) + sc - v;
  ncur[tid] = excl;
  int node0 = (b << BSHIFT) + tid;
  if (node0 < N_NODES) csr[node0] = ebase + excl;
  if (b == 0 && tid == 0) csr[N_NODES] = N_EDGES;
  __syncthreads();
  for (int i = tid; i < myCnt; i += 512) {
    unsigned int pe = srcp[i];
    int pos = atomicAdd(&ncur[pe >> 17], 1);
    ssrc[ebase + pos] = (int)(pe & 0x1FFFF);
  }
}

// ---------------- aggregation (bf16 in/out, f32 accum), deep-unrolled ----------------

__global__ __launch_bounds__(256) void agg1_kernel(const uint2* __restrict__ x,
                                                   const int* __restrict__ csr,
                                                   const int* __restrict__ ssrc,
                                                   uint2* __restrict__ out) {
  int node = blockIdx.x * 4 + (threadIdx.x >> 6);
  int lane = threadIdx.x & 63;
  int half = lane >> 5;        // which edge of each pair
  int dl   = lane & 31;        // dims dl*4 .. dl*4+3
  float a0 = 0.f, a1 = 0.f, a2 = 0.f, a3 = 0.f;
  if (half == 0) {             // self term once
    uint2 u = x[(size_t)node * 32 + dl];
    a0 = bf_lo(u.x); a1 = bf_hi(u.x); a2 = bf_lo(u.y); a3 = bf_hi(u.y);
  }
  int s = csr[node], e = csr[node + 1];
  int i = s;
  for (; i + 8 <= e; i += 8) {
    int s0 = ssrc[i + half],     s1 = ssrc[i + 2 + half];
    int s2 = ssrc[i + 4 + half], s3 = ssrc[i + 6 + half];
    uint2 v0 = x[(size_t)s0 * 32 + dl];
    uint2 v1 = x[(size_t)s1 * 32 + dl];
    uint2 v2 = x[(size_t)s2 * 32 + dl];
    uint2 v3 = x[(size_t)s3 * 32 + dl];
    a0 += bf_lo(v0.x) + bf_lo(v1.x) + bf_lo(v2.x) + bf_lo(v3.x);
    a1 += bf_hi(v0.x) + bf_hi(v1.x) + bf_hi(v2.x) + bf_hi(v3.x);
    a2 += bf_lo(v0.y) + bf_lo(v1.y) + bf_lo(v2.y) + bf_lo(v3.y);
    a3 += bf_hi(v0.y) + bf_hi(v1.y) + bf_hi(v2.y) + bf_hi(v3.y);
  }
  for (; i + 2 <= e; i += 2) {
    int sn = ssrc[i + half];
    uint2 v = x[(size_t)sn * 32 + dl];
    a0 += bf_lo(v.x); a1 += bf_hi(v.x);
    a2 += bf_lo(v.y); a3 += bf_hi(v.y);
  }
  if (i < e && half == 0) {    // odd tail
    uint2 v = x[(size_t)ssrc[i] * 32 + dl];
    a0 += bf_lo(v.x); a1 += bf_hi(v.x);
    a2 += bf_lo(v.y); a3 += bf_hi(v.y);
  }
  a0 += __shfl_xor(a0, 32);
  a1 += __shfl_xor(a1, 32);
  a2 += __shfl_xor(a2, 32);
  a3 += __shfl_xor(a3, 32);
  if (half == 0) {
    uint2 o;
    o.x = packbf(a0, a1);
    o.y = packbf(a2, a3);
    out[(size_t)node * 32 + dl] = o;
  }
}

__global__ __launch_bounds__(256) void agg2_kernel(const uint2* __restrict__ x,
                                                   const int* __restrict__ csr,
                                                   const int* __restrict__ ssrc,
                                                   uint2* __restrict__ out) {
  int node = blockIdx.x * 4 + (threadIdx.x >> 6);
  int lane = threadIdx.x & 63;
  uint2 u = x[(size_t)node * 64 + lane];
  float a0 = bf_lo(u.x), a1 = bf_hi(u.x), a2 = bf_lo(u.y), a3 = bf_hi(u.y);
  int s = csr[node], e = csr[node + 1];
  int i = s;
  for (; i + 8 <= e; i += 8) {
    int n0 = ssrc[i],     n1 = ssrc[i + 1], n2 = ssrc[i + 2], n3 = ssrc[i + 3];
    int n4 = ssrc[i + 4], n5 = ssrc[i + 5], n6 = ssrc[i + 6], n7 = ssrc[i + 7];
    uint2 v0 = x[(size_t)n0 * 64 + lane];
    uint2 v1 = x[(size_t)n1 * 64 + lane];
    uint2 v2 = x[(size_t)n2 * 64 + lane];
    uint2 v3 = x[(size_t)n3 * 64 + lane];
    uint2 v4 = x[(size_t)n4 * 64 + lane];
    uint2 v5 = x[(size_t)n5 * 64 + lane];
    uint2 v6 = x[(size_t)n6 * 64 + lane];
    uint2 v7 = x[(size_t)n7 * 64 + lane];
    a0 += (bf_lo(v0.x) + bf_lo(v1.x)) + (bf_lo(v2.x) + bf_lo(v3.x)) +
          (bf_lo(v4.x) + bf_lo(v5.x)) + (bf_lo(v6.x) + bf_lo(v7.x));
    a1 += (bf_hi(v0.x) + bf_hi(v1.x)) + (bf_hi(v2.x) + bf_hi(v3.x)) +
          (bf_hi(v4.x) + bf_hi(v5.x)) + (bf_hi(v6.x) + bf_hi(v7.x));
    a2 += (bf_lo(v0.y) + bf_lo(v1.y)) + (bf_lo(v2.y) + bf_lo(v3.y)) +
          (bf_lo(v4.y) + bf_lo(v5.y)) + (bf_lo(v6.y) + bf_lo(v7.y));
    a3 += (bf_hi(v0.y) + bf_hi(v1.y)) + (bf_hi(v2.y) + bf_hi(v3.y)) +
          (bf_hi(v4.y) + bf_hi(v5.y)) + (bf_hi(v6.y) + bf_hi(v7.y));
  }
  for (; i < e; i++) {
    uint2 v = x[(size_t)ssrc[i] * 64 + lane];
    a0 += bf_lo(v.x); a1 += bf_hi(v.x);
    a2 += bf_lo(v.y); a3 += bf_hi(v.y);
  }
  uint2 o;
  o.x = packbf(a0, a1);
  o.y = packbf(a2, a3);
  out[(size_t)node * 64 + lane] = o;
}

// ---------------- GEMM: 128 rows x 256 cols per block, 8 waves, BK=64 ----------------
// Col-merged: A read ONCE from HBM. LDS 48 KB caps occupancy at 3 blocks/CU
// naturally — NO min-waves launch bound (r13's (512,6) spilled the MFMA
// accumulators to scratch: VGPR 40 < the 64 acc needs, 464 MB scratch writes).

template<int K, bool RELU>
__global__ __launch_bounds__(512)
void gemm128(const unsigned short* __restrict__ A,
             const unsigned short* __restrict__ Wt,
             const float* __restrict__ bias,
             unsigned short* __restrict__ C) {
  __shared__ unsigned short Asl[128 * 64];   // 16 KB
  __shared__ unsigned short Wsl[256 * 64];   // 32 KB
  const int tid = threadIdx.x;
  const int lane = tid & 63;
  const int w = tid >> 6;          // 0..7
  const int wm = w >> 2;           // 0..1 (row half)
  const int wn = w & 3;            // 0..3 (col quarter)
  const int l15 = lane & 15, l4 = lane >> 4, l7 = lane & 7;
  const int rowBase = blockIdx.x * 128;

  f32x4 acc[4][4] = {};

  for (int k0 = 0; k0 < K; k0 += 64) {
#pragma unroll
    for (int i = 0; i < 2; i++) {            // stage A: 1024 chunks of 16B
      int c = i * 512 + tid;
      int m = c >> 3, koL = c & 7;
      int koS = koL ^ (m & 7);
      int gr = rowBase + m; if (gr >= N_NODES) gr = N_NODES - 1;
      gload16(&A[(size_t)gr * K + k0 + koS * 8], Asl + (size_t)c * 8);
    }
#pragma unroll
    for (int i = 0; i < 4; i++) {            // stage W: 2048 chunks of 16B
      int c = i * 512 + tid;
      int n = c >> 3, koL = c & 7;
      int koS = koL ^ (n & 7);
      gload16(&Wt[(size_t)n * K + k0 + koS * 8], Wsl + (size_t)c * 8);
    }
    __syncthreads();
#pragma unroll
    for (int kk = 0; kk < 2; kk++) {
      int koX = (kk * 4 + l4) ^ l7;
      bf16x8 a[4], b[4];
#pragma unroll
      for (int f = 0; f < 4; f++) {
        int rowA = wm * 64 + f * 16 + l15;
        int rowB = wn * 64 + f * 16 + l15;
        a[f] = *(const bf16x8*)&Asl[(size_t)(rowA * 64 + koX * 8)];
        b[f] = *(const bf16x8*)&Wsl[(size_t)(rowB * 64 + koX * 8)];
      }
#pragma unroll
      for (int fm = 0; fm < 4; fm++)
#pragma unroll
        for (int fn = 0; fn < 4; fn++)
          acc[fm][fn] = __builtin_amdgcn_mfma_f32_16x16x32_bf16(a[fm], b[fn], acc[fm][fn], 0, 0, 0);
    }
    __syncthreads();
  }

#pragma unroll
  for (int fm = 0; fm < 4; fm++) {
    int r0 = rowBase + wm * 64 + fm * 16 + l4 * 4;
#pragma unroll
    for (int fn = 0; fn < 4; fn++) {
      int col = wn * 64 + fn * 16 + l15;
      float bb = bias[col];
#pragma unroll
      for (int j = 0; j < 4; j++) {
        int r = r0 + j;
        if (r < N_NODES) {
          float v = acc[fm][fn][j] + bb;
          if (RELU) v = fmaxf(v, 0.f);
          C[(size_t)r * HID + col] = f2bf(v);
        }
      }
    }
  }
}

// ---------------- pooling ----------------

__global__ __launch_bounds__(256) void pool_kernel(const unsigned short* __restrict__ H,
                                                   const int* __restrict__ batch,
                                                   float* __restrict__ sums,
                                                   float* __restrict__ cnts) {
  int d = threadIdx.x;
  int n0 = blockIdx.x * 128;
  int n1 = n0 + 128; if (n1 > N_NODES) n1 = N_NODES;
  int cur = batch[n0];
  float run = 0.f, runc = 0.f;
  for (int i = n0; i < n1; i++) {
    int b = batch[i];
    if (b != cur) {
      atomicAdd(&sums[(size_t)cur * HID + d], run);
      if (d == 0) atomicAdd(&cnts[cur], runc);
      run = 0.f; runc = 0.f; cur = b;
    }
    run += __uint_as_float(((unsigned int)H[(size_t)i * HID + d]) << 16);
    runc += 1.f;
  }
  atomicAdd(&sums[(size_t)cur * HID + d], run);
  if (d == 0) atomicAdd(&cnts[cur], runc);
}

// ---------------- head: relu(g@wf1+bf1)@wf2+bf2, 8-deep ILP ----------------

__global__ __launch_bounds__(256) void head_kernel(const float* __restrict__ sums,
                                                   const float* __restrict__ cnts,
                                                   const float* __restrict__ gattr,
                                                   const float* __restrict__ wf1,
                                                   const float* __restrict__ bf1,
                                                   const float* __restrict__ wf2,
                                                   const float* __restrict__ bf2,
                                                   float* __restrict__ out) {
  int g = blockIdx.x, tid = threadIdx.x;
  __shared__ float gv[HID + GA + 2];   // 262 + pad
  __shared__ float red[256];
  float c = cnts[g]; c = fmaxf(c, 1.0f);
  gv[tid] = sums[(size_t)g * HID + tid] / c;
  if (tid < GA) gv[HID + tid] = gattr[g * GA + tid];
  if (tid < 2) gv[HID + GA + tid] = 0.f;
  __syncthreads();
  float ac0 = 0.f, ac1 = 0.f, ac2 = 0.f, ac3 = 0.f;
  float ac4 = 0.f, ac5 = 0.f, ac6 = 0.f, ac7 = 0.f;
  const float* wcol = wf1 + tid;
  int k = 0;
#pragma unroll 1
  for (; k + 8 <= HID + GA; k += 8) {
    float w0 = wcol[(size_t)(k + 0) * HID];
    float w1 = wcol[(size_t)(k + 1) * HID];
    float w2 = wcol[(size_t)(k + 2) * HID];
    float w3 = wcol[(size_t)(k + 3) * HID];
    float w4 = wcol[(size_t)(k + 4) * HID];
    float w5 = wcol[(size_t)(k + 5) * HID];
    float w6 = wcol[(size_t)(k + 6) * HID];
    float w7 = wcol[(size_t)(k + 7) * HID];
    ac0 = fmaf(gv[k + 0], w0, ac0);
    ac1 = fmaf(gv[k + 1], w1, ac1);
    ac2 = fmaf(gv[k + 2], w2, ac2);
    ac3 = fmaf(gv[k + 3], w3, ac3);
    ac4 = fmaf(gv[k + 4], w4, ac4);
    ac5 = fmaf(gv[k + 5], w5, ac5);
    ac6 = fmaf(gv[k + 6], w6, ac6);
    ac7 = fmaf(gv[k + 7], w7, ac7);
  }
  for (; k < HID + GA; k++)
    ac0 = fmaf(gv[k], wcol[(size_t)k * HID], ac0);
  float acc = ((ac0 + ac1) + (ac2 + ac3)) + ((ac4 + ac5) + (ac6 + ac7)) + bf1[tid];
  float h = fmaxf(acc, 0.f);
  red[tid] = h * wf2[tid];
  __syncthreads();
  for (int s = 128; s > 0; s >>= 1) {
    if (tid < s) red[tid] += red[tid + s];
    __syncthreads();
  }
  if (tid == 0) out[g] = red[0] + bf2[0];
}

// ---------------- launch ----------------

extern "C" void kernel_launch(void* const* d_in, const int* in_sizes, int n_in,
                              void* d_out, int out_size, void* d_ws, size_t ws_size,
                              hipStream_t stream) {
  const float* x     = (const float*)d_in[0];
  const int*   eidx  = (const int*)d_in[1];
  const int*   batch = (const int*)d_in[2];
  const float* gattr = (const float*)d_in[3];
  const float* w1a = (const float*)d_in[4];  const float* b1a = (const float*)d_in[5];
  const float* w1b = (const float*)d_in[6];  const float* b1b = (const float*)d_in[7];
  const float* w2a = (const float*)d_in[8];  const float* b2a = (const float*)d_in[9];
  const float* w2b = (const float*)d_in[10]; const float* b2b = (const float*)d_in[11];
  const float* wf1 = (const float*)d_in[12]; const float* bf1 = (const float*)d_in[13];
  const float* wf2 = (const float*)d_in[14]; const float* bf2 = (const float*)d_in[15];
  float* out = (float*)d_out;

  const int* esrc = eidx;
  const int* edst = eidx + N_EDGES;

  char* w = (char*)d_ws;
  auto alloc = [&](size_t bytes) -> void* {
    void* p = (void*)w;
    w += (bytes + 255) & ~(size_t)255;
    return p;
  };
  unsigned short* B0 = (unsigned short*)alloc((size_t)N_NODES * DIN * 2);  // x bf16
  unsigned short* B1 = (unsigned short*)alloc((size_t)N_NODES * HID * 2);  // agg out
  unsigned short* B2 = (unsigned short*)alloc((size_t)N_NODES * HID * 2);  // conv out
  unsigned short* B3 = (unsigned short*)alloc((size_t)N_NODES * HID * 2);  // h1
  unsigned short* w1aT = (unsigned short*)alloc(256 * 128 * 2);
  unsigned short* w1bT = (unsigned short*)alloc(256 * 256 * 2);
  unsigned short* w2aT = (unsigned short*)alloc(256 * 256 * 2);
  unsigned short* w2bT = (unsigned short*)alloc(256 * 256 * 2);
  int*   csr    = (int*)alloc((N_NODES + 4) * 4);
  int*   cursor = (int*)alloc(NBUCK * 4);
  unsigned int* tmp = (unsigned int*)alloc((size_t)NBUCK * BCAP * 4);
  int*   ssrc   = (int*)alloc((size_t)N_EDGES * 4);
  float* sums   = (float*)alloc((size_t)NGRAPH * HID * 4);
  float* cnts   = (float*)alloc(NGRAPH * 4);

  hipMemsetAsync(cursor, 0, NBUCK * 4, stream);
  hipMemsetAsync(sums, 0, (size_t)NGRAPH * HID * 4 + 256, stream);  // sums + cnts

  cvt_all<<<12500 + 896, 256, 0, stream>>>(x, w1a, w1b, w2a, w2b,
                                           B0, w1aT, w1bT, w2aT, w2bT);

  bin_kernel<<<(N_EDGES + 4095) / 4096, 256, 0, stream>>>(esrc, edst, cursor, tmp);
  sort_kernel<<<NBUCK, 512, 0, stream>>>(tmp, cursor, csr, ssrc);

  const int ngemm = (N_NODES + 127) / 128;   // 782 blocks (full 256-col tiles)

  // conv1: agg(x) -> B1[N][128]; relu(B1@W1a+b) -> B3; relu(B3@W1b+b) -> B2
  agg1_kernel<<<N_NODES / 4, 256, 0, stream>>>((const uint2*)B0, csr, ssrc, (uint2*)B1);
  gemm128<128, true><<<ngemm, 512, 0, stream>>>(B1, w1aT, b1a, B3);
  gemm128<256, true><<<ngemm, 512, 0, stream>>>(B3, w1bT, b1b, B2);
  // conv2: agg(B2) -> B1[N][256]; relu(B1@W2a+b) -> B3; B3@W2b+b -> B2
  agg2_kernel<<<N_NODES / 4, 256, 0, stream>>>((const uint2*)B2, csr, ssrc, (uint2*)B1);
  gemm128<256, true><<<ngemm, 512, 0, stream>>>(B1, w2aT, b2a, B3);
  gemm128<256, false><<<ngemm, 512, 0, stream>>>(B3, w2bT, b2b, B2);

  pool_kernel<<<(N_NODES + 127) / 128, 256, 0, stream>>>(B2, batch, sums, cnts);
  head_kernel<<<NGRAPH, 256, 0, stream>>>(sums, cnts, gattr, wf1, bf1, wf2, bf2, out);
}

// Round 15
// 403.644 us; speedup vs baseline: 2.3518x; 1.0195x over previous
//
#include <hip/hip_runtime.h>

#define N_NODES 100000
#define N_EDGES 1600000
#define NGRAPH  64
#define DIN     128
#define HID     256
#define GA      6

// bucketed CSR build
#define NBUCK  196       // ceil(100000 / 512)
#define BSHIFT 9         // 512 nodes per bucket
#define BCAP   10240     // per-bucket capacity (mean 8192, +22 sigma)

typedef __attribute__((ext_vector_type(8))) short bf16x8;
typedef __attribute__((ext_vector_type(4))) float f32x4;

__device__ __forceinline__ unsigned short f2bf(float f) {
  unsigned int u = __float_as_uint(f);
  u += 0x7fffu + ((u >> 16) & 1u);
  return (unsigned short)(u >> 16);
}
__device__ __forceinline__ float bf_lo(unsigned int u) { return __uint_as_float(u << 16); }
__device__ __forceinline__ float bf_hi(unsigned int u) { return __uint_as_float(u & 0xffff0000u); }
__device__ __forceinline__ unsigned int packbf(float lo, float hi) {
  return (unsigned int)f2bf(lo) | ((unsigned int)f2bf(hi) << 16);
}

__device__ __forceinline__ void gload16(const void* g, void* l) {
  __builtin_amdgcn_global_load_lds(
      (const __attribute__((address_space(1))) unsigned int*)g,
      (__attribute__((address_space(3))) unsigned int*)l, 16, 0, 0);
}

// ---------------- prep: all f32 -> bf16 conversions in ONE launch ----------------

__global__ __launch_bounds__(256) void cvt_all(const float* __restrict__ x,
                                               const float* __restrict__ w1a,
                                               const float* __restrict__ w1b,
                                               const float* __restrict__ w2a,
                                               const float* __restrict__ w2b,
                                               unsigned short* __restrict__ xo,
                                               unsigned short* __restrict__ o1a,
                                               unsigned short* __restrict__ o1b,
                                               unsigned short* __restrict__ o2a,
                                               unsigned short* __restrict__ o2b) {
  int bid = blockIdx.x, tid = threadIdx.x;
  if (bid < 12500) {                       // x: 12.8M elems, 4/thread
    size_t idx = ((size_t)bid * 256 + tid) * 4;
    float4 v = *(const float4*)&x[idx];
    ushort4 o;
    o.x = f2bf(v.x); o.y = f2bf(v.y); o.z = f2bf(v.z); o.w = f2bf(v.w);
    *(ushort4*)&xo[idx] = o;
    return;
  }
  bid -= 12500;
  const float* in; unsigned short* out; int shift, idx;
  if (bid < 128)      { in = w1a; out = o1a; shift = 7; idx = bid * 256 + tid; }
  else if (bid < 384) { in = w1b; out = o1b; shift = 8; idx = (bid - 128) * 256 + tid; }
  else if (bid < 640) { in = w2a; out = o2a; shift = 8; idx = (bid - 384) * 256 + tid; }
  else                { in = w2b; out = o2b; shift = 8; idx = (bid - 640) * 256 + tid; }
  int K = 1 << shift;
  int n = idx >> shift;
  int k = idx & (K - 1);
  out[idx] = f2bf(in[(size_t)k * HID + n]);
}

// ---------------- pass 1: bin edges by dst>>9 with block-local rank ----------------

__global__ __launch_bounds__(256) void bin_kernel(const int* __restrict__ esrc,
                                                  const int* __restrict__ edst,
                                                  int* __restrict__ cursor,
                                                  unsigned int* __restrict__ tmp) {
  __shared__ unsigned int pk[4096];
  __shared__ unsigned char bkb[4096];
  __shared__ int hist[NBUCK], lbase[NBUCK + 1], gbase[NBUCK], lcur[NBUCK];
  const int tid = threadIdx.x;
  const int lane = tid & 63;
  const int ebase = blockIdx.x * 4096;
  const int n = min(4096, N_EDGES - ebase);
  if (tid < NBUCK) hist[tid] = 0;
  __syncthreads();
  unsigned int pkv[16]; int bk[16];
#pragma unroll
  for (int i = 0; i < 16; i++) {
    int e = ebase + i * 256 + tid;
    bk[i] = -1;
    if (e < N_EDGES) {
      int s = esrc[e], d = edst[e];
      bk[i] = d >> BSHIFT;
      pkv[i] = (unsigned int)s | ((unsigned int)(d & ((1 << BSHIFT) - 1)) << 17);
      atomicAdd(&hist[bk[i]], 1);
    }
  }
  __syncthreads();
  if (tid < 64) {                 // 4-per-lane exclusive scan of NBUCK counts
    int i0 = 4 * tid;
    int a0 = (i0 + 0 < NBUCK) ? hist[i0 + 0] : 0;
    int a1 = (i0 + 1 < NBUCK) ? hist[i0 + 1] : 0;
    int a2 = (i0 + 2 < NBUCK) ? hist[i0 + 2] : 0;
    int a3 = (i0 + 3 < NBUCK) ? hist[i0 + 3] : 0;
    int p = a0 + a1 + a2 + a3, sc = p;
#pragma unroll
    for (int off = 1; off < 64; off <<= 1) {
      int t = __shfl_up(sc, off);
      if (lane >= off) sc += t;
    }
    int excl = sc - p;
    if (i0 + 0 < NBUCK) lbase[i0 + 0] = excl;
    if (i0 + 1 < NBUCK) lbase[i0 + 1] = excl + a0;
    if (i0 + 2 < NBUCK) lbase[i0 + 2] = excl + a0 + a1;
    if (i0 + 3 < NBUCK) lbase[i0 + 3] = excl + a0 + a1 + a2;
    if (tid == 63) lbase[NBUCK] = sc;
  }
  __syncthreads();
  if (tid < NBUCK) {
    int c = hist[tid];
    gbase[tid] = c ? atomicAdd(&cursor[tid], c) : 0;
    lcur[tid] = lbase[tid];
  }
  __syncthreads();
#pragma unroll
  for (int i = 0; i < 16; i++) {
    if (bk[i] >= 0) {
      int pos = atomicAdd(&lcur[bk[i]], 1);
      pk[pos] = pkv[i];
      bkb[pos] = (unsigned char)bk[i];
    }
  }
  __syncthreads();
#pragma unroll
  for (int i = 0; i < 16; i++) {
    int idx = i * 256 + tid;
    if (idx < n) {
      int b = bkb[idx];
      tmp[(size_t)b * BCAP + gbase[b] + (idx - lbase[b])] = pk[idx];
    }
  }
}

// ---------------- pass 2: per-bucket counting sort -> csr + ssrc ----------------

__global__ __launch_bounds__(512) void sort_kernel(const unsigned int* __restrict__ tmp,
                                                   const int* __restrict__ cnt,
                                                   int* __restrict__ csr,
                                                   int* __restrict__ ssrc) {
  __shared__ int nhist[512], ncur[512];
  __shared__ int bb[NBUCK];
  __shared__ int wsum[8];
  const int b = blockIdx.x;
  const int tid = threadIdx.x;
  const int lane = tid & 63, wid = tid >> 6;
  if (tid < 64) {                 // 4-per-lane scan of bucket counts -> edge bases
    int i0 = 4 * tid;
    int a0 = (i0 + 0 < NBUCK) ? cnt[i0 + 0] : 0;
    int a1 = (i0 + 1 < NBUCK) ? cnt[i0 + 1] : 0;
    int a2 = (i0 + 2 < NBUCK) ? cnt[i0 + 2] : 0;
    int a3 = (i0 + 3 < NBUCK) ? cnt[i0 + 3] : 0;
    int p = a0 + a1 + a2 + a3, sc = p;
#pragma unroll
    for (int off = 1; off < 64; off <<= 1) {
      int t = __shfl_up(sc, off);
      if (lane >= off) sc += t;
    }
    int excl = sc - p;
    if (i0 + 0 < NBUCK) bb[i0 + 0] = excl;
    if (i0 + 1 < NBUCK) bb[i0 + 1] = excl + a0;
    if (i0 + 2 < NBUCK) bb[i0 + 2] = excl + a0 + a1;
    if (i0 + 3 < NBUCK) bb[i0 + 3] = excl + a0 + a1 + a2;
  }
  nhist[tid] = 0;
  __syncthreads();
  const int myCnt = cnt[b];
  const int ebase = bb[b];
  const unsigned int* srcp = tmp + (size_t)b * BCAP;
  for (int i = tid; i < myCnt; i += 512)
    atomicAdd(&nhist[srcp[i] >> 17], 1);
  __syncthreads();
  // block scan of 512 node counts (1/thread, 8 waves)
  int v = nhist[tid];
  int sc = v;
#pragma unroll
  for (int off = 1; off < 64; off <<= 1) {
    int t = __shfl_up(sc, off);
    if (lane >= off) sc += t;
  }
  if (lane == 63) wsum[wid] = sc;
  __syncthreads();
  if (tid < 8) {
    int ws = wsum[tid];
#pragma unroll
    for (int off = 1; off < 8; off <<= 1) {
      int t = __shfl_up(ws, off);
      if (tid >= off) ws += t;
    }
    wsum[tid] = ws;
  }
  __syncthreads();
  int excl = ((wid > 0) ? wsum[wid - 1] : 0) + sc - v;
  ncur[tid] = excl;
  int node0 = (b << BSHIFT) + tid;
  if (node0 < N_NODES) csr[node0] = ebase + excl;
  if (b == 0 && tid == 0) csr[N_NODES] = N_EDGES;
  __syncthreads();
  for (int i = tid; i < myCnt; i += 512) {
    unsigned int pe = srcp[i];
    int pos = atomicAdd(&ncur[pe >> 17], 1);
    ssrc[ebase + pos] = (int)(pe & 0x1FFFF);
  }
}

// ---------------- aggregation (bf16 in/out, f32 accum), deep-unrolled ----------------

__global__ __launch_bounds__(256) void agg1_kernel(const uint2* __restrict__ x,
                                                   const int* __restrict__ csr,
                                                   const int* __restrict__ ssrc,
                                                   uint2* __restrict__ out) {
  int node = blockIdx.x * 4 + (threadIdx.x >> 6);
  int lane = threadIdx.x & 63;
  int half = lane >> 5;        // which edge of each pair
  int dl   = lane & 31;        // dims dl*4 .. dl*4+3
  float a0 = 0.f, a1 = 0.f, a2 = 0.f, a3 = 0.f;
  if (half == 0) {             // self term once
    uint2 u = x[(size_t)node * 32 + dl];
    a0 = bf_lo(u.x); a1 = bf_hi(u.x); a2 = bf_lo(u.y); a3 = bf_hi(u.y);
  }
  int s = csr[node], e = csr[node + 1];
  int i = s;
  for (; i + 8 <= e; i += 8) {
    int s0 = ssrc[i + half],     s1 = ssrc[i + 2 + half];
    int s2 = ssrc[i + 4 + half], s3 = ssrc[i + 6 + half];
    uint2 v0 = x[(size_t)s0 * 32 + dl];
    uint2 v1 = x[(size_t)s1 * 32 + dl];
    uint2 v2 = x[(size_t)s2 * 32 + dl];
    uint2 v3 = x[(size_t)s3 * 32 + dl];
    a0 += bf_lo(v0.x) + bf_lo(v1.x) + bf_lo(v2.x) + bf_lo(v3.x);
    a1 += bf_hi(v0.x) + bf_hi(v1.x) + bf_hi(v2.x) + bf_hi(v3.x);
    a2 += bf_lo(v0.y) + bf_lo(v1.y) + bf_lo(v2.y) + bf_lo(v3.y);
    a3 += bf_hi(v0.y) + bf_hi(v1.y) + bf_hi(v2.y) + bf_hi(v3.y);
  }
  for (; i + 2 <= e; i += 2) {
    int sn = ssrc[i + half];
    uint2 v = x[(size_t)sn * 32 + dl];
    a0 += bf_lo(v.x); a1 += bf_hi(v.x);
    a2 += bf_lo(v.y); a3 += bf_hi(v.y);
  }
  if (i < e && half == 0) {    // odd tail
    uint2 v = x[(size_t)ssrc[i] * 32 + dl];
    a0 += bf_lo(v.x); a1 += bf_hi(v.x);
    a2 += bf_lo(v.y); a3 += bf_hi(v.y);
  }
  a0 += __shfl_xor(a0, 32);
  a1 += __shfl_xor(a1, 32);
  a2 += __shfl_xor(a2, 32);
  a3 += __shfl_xor(a3, 32);
  if (half == 0) {
    uint2 o;
    o.x = packbf(a0, a1);
    o.y = packbf(a2, a3);
    out[(size_t)node * 32 + dl] = o;
  }
}

__global__ __launch_bounds__(256) void agg2_kernel(const uint2* __restrict__ x,
                                                   const int* __restrict__ csr,
                                                   const int* __restrict__ ssrc,
                                                   uint2* __restrict__ out) {
  int node = blockIdx.x * 4 + (threadIdx.x >> 6);
  int lane = threadIdx.x & 63;
  uint2 u = x[(size_t)node * 64 + lane];
  float a0 = bf_lo(u.x), a1 = bf_hi(u.x), a2 = bf_lo(u.y), a3 = bf_hi(u.y);
  int s = csr[node], e = csr[node + 1];
  int i = s;
  for (; i + 8 <= e; i += 8) {
    int n0 = ssrc[i],     n1 = ssrc[i + 1], n2 = ssrc[i + 2], n3 = ssrc[i + 3];
    int n4 = ssrc[i + 4], n5 = ssrc[i + 5], n6 = ssrc[i + 6], n7 = ssrc[i + 7];
    uint2 v0 = x[(size_t)n0 * 64 + lane];
    uint2 v1 = x[(size_t)n1 * 64 + lane];
    uint2 v2 = x[(size_t)n2 * 64 + lane];
    uint2 v3 = x[(size_t)n3 * 64 + lane];
    uint2 v4 = x[(size_t)n4 * 64 + lane];
    uint2 v5 = x[(size_t)n5 * 64 + lane];
    uint2 v6 = x[(size_t)n6 * 64 + lane];
    uint2 v7 = x[(size_t)n7 * 64 + lane];
    a0 += (bf_lo(v0.x) + bf_lo(v1.x)) + (bf_lo(v2.x) + bf_lo(v3.x)) +
          (bf_lo(v4.x) + bf_lo(v5.x)) + (bf_lo(v6.x) + bf_lo(v7.x));
    a1 += (bf_hi(v0.x) + bf_hi(v1.x)) + (bf_hi(v2.x) + bf_hi(v3.x)) +
          (bf_hi(v4.x) + bf_hi(v5.x)) + (bf_hi(v6.x) + bf_hi(v7.x));
    a2 += (bf_lo(v0.y) + bf_lo(v1.y)) + (bf_lo(v2.y) + bf_lo(v3.y)) +
          (bf_lo(v4.y) + bf_lo(v5.y)) + (bf_lo(v6.y) + bf_lo(v7.y));
    a3 += (bf_hi(v0.y) + bf_hi(v1.y)) + (bf_hi(v2.y) + bf_hi(v3.y)) +
          (bf_hi(v4.y) + bf_hi(v5.y)) + (bf_hi(v6.y) + bf_hi(v7.y));
  }
  for (; i < e; i++) {
    uint2 v = x[(size_t)ssrc[i] * 64 + lane];
    a0 += bf_lo(v.x); a1 += bf_hi(v.x);
    a2 += bf_lo(v.y); a3 += bf_hi(v.y);
  }
  uint2 o;
  o.x = packbf(a0, a1);
  o.y = packbf(a2, a3);
  out[(size_t)node * 64 + lane] = o;
}

// ---------------- GEMM: 128 rows x 256 cols, 8 waves, BK=64 ----------------
// POOL=true (final GEMM): skip C write; accumulate per-graph column sums via
// LDS per-graph partials (<=GMAX graphs per 128-row block; batch sorted,
// graph size ~1563 >> 128) + one global atomicAdd per (graph,col) per block.
// NO min-waves bound (r13 lesson: (512,6) spilled MFMA accumulators).

#define GMAX 4

template<int K, bool RELU, bool POOL>
__global__ __launch_bounds__(512)
void gemm128(const unsigned short* __restrict__ A,
             const unsigned short* __restrict__ Wt,
             const float* __restrict__ bias,
             unsigned short* __restrict__ C,
             const int* __restrict__ batch,
             float* __restrict__ sums) {
  __shared__ unsigned short Asl[128 * 64];   // 16 KB
  __shared__ unsigned short Wsl[256 * 64];   // 32 KB
  __shared__ float psum[POOL ? GMAX * HID : 1];  // 4 KB (POOL only)
  const int tid = threadIdx.x;
  const int lane = tid & 63;
  const int w = tid >> 6;          // 0..7
  const int wm = w >> 2;           // 0..1 (row half)
  const int wn = w & 3;            // 0..3 (col quarter)
  const int l15 = lane & 15, l4 = lane >> 4, l7 = lane & 7;
  const int rowBase = blockIdx.x * 128;

  if (POOL) {
#pragma unroll
    for (int i = tid; i < GMAX * HID; i += 512) psum[i] = 0.f;
  }

  f32x4 acc[4][4] = {};

  for (int k0 = 0; k0 < K; k0 += 64) {
#pragma unroll
    for (int i = 0; i < 2; i++) {            // stage A: 1024 chunks of 16B
      int c = i * 512 + tid;
      int m = c >> 3, koL = c & 7;
      int koS = koL ^ (m & 7);
      int gr = rowBase + m; if (gr >= N_NODES) gr = N_NODES - 1;
      gload16(&A[(size_t)gr * K + k0 + koS * 8], Asl + (size_t)c * 8);
    }
#pragma unroll
    for (int i = 0; i < 4; i++) {            // stage W: 2048 chunks of 16B
      int c = i * 512 + tid;
      int n = c >> 3, koL = c & 7;
      int koS = koL ^ (n & 7);
      gload16(&Wt[(size_t)n * K + k0 + koS * 8], Wsl + (size_t)c * 8);
    }
    __syncthreads();
#pragma unroll
    for (int kk = 0; kk < 2; kk++) {
      int koX = (kk * 4 + l4) ^ l7;
      bf16x8 a[4], b[4];
#pragma unroll
      for (int f = 0; f < 4; f++) {
        int rowA = wm * 64 + f * 16 + l15;
        int rowB = wn * 64 + f * 16 + l15;
        a[f] = *(const bf16x8*)&Asl[(size_t)(rowA * 64 + koX * 8)];
        b[f] = *(const bf16x8*)&Wsl[(size_t)(rowB * 64 + koX * 8)];
      }
#pragma unroll
      for (int fm = 0; fm < 4; fm++)
#pragma unroll
        for (int fn = 0; fn < 4; fn++)
          acc[fm][fn] = __builtin_amdgcn_mfma_f32_16x16x32_bf16(a[fm], b[fn], acc[fm][fn], 0, 0, 0);
    }
    __syncthreads();
  }

  if (!POOL) {
    // normal epilogue: bias (+relu), bf16 store
#pragma unroll
    for (int fm = 0; fm < 4; fm++) {
      int r0 = rowBase + wm * 64 + fm * 16 + l4 * 4;
#pragma unroll
      for (int fn = 0; fn < 4; fn++) {
        int col = wn * 64 + fn * 16 + l15;
        float bb = bias[col];
#pragma unroll
        for (int j = 0; j < 4; j++) {
          int r = r0 + j;
          if (r < N_NODES) {
            float v = acc[fm][fn][j] + bb;
            if (RELU) v = fmaxf(v, 0.f);
            C[(size_t)r * HID + col] = f2bf(v);
          }
        }
      }
    }
  } else {
    // fused mean-pool epilogue: accumulate f32 per-graph partials
    const int g0 = batch[rowBase];
#pragma unroll
    for (int fn = 0; fn < 4; fn++) {
      int col = wn * 64 + fn * 16 + l15;
      float bb = bias[col];
      float part = 0.f;
      int curgi = -1;
#pragma unroll
      for (int fm = 0; fm < 4; fm++) {
#pragma unroll
        for (int j = 0; j < 4; j++) {
          int r = rowBase + wm * 64 + fm * 16 + l4 * 4 + j;
          if (r < N_NODES) {
            float v = acc[fm][fn][j] + bb;
            int gi = batch[r] - g0;
            if (gi != curgi) {
              if (curgi >= 0) {
                if (curgi < GMAX) atomicAdd(&psum[curgi * HID + col], part);
                else atomicAdd(&sums[(size_t)(g0 + curgi) * HID + col], part);
              }
              curgi = gi; part = 0.f;
            }
            part += v;
          }
        }
      }
      if (curgi >= 0) {
        if (curgi < GMAX) atomicAdd(&psum[curgi * HID + col], part);
        else atomicAdd(&sums[(size_t)(g0 + curgi) * HID + col], part);
      }
    }
    __syncthreads();
#pragma unroll
    for (int i = tid; i < GMAX * HID; i += 512) {
      float v = psum[i];
      int g = g0 + (i >> 8);
      if (v != 0.f && g < NGRAPH)
        atomicAdd(&sums[(size_t)g * HID + (i & 255)], v);
    }
  }
}

// ---------------- head: mean + relu(g@wf1+bf1)@wf2+bf2; counts via binary search ----------------

__global__ __launch_bounds__(256) void head_kernel(const float* __restrict__ sums,
                                                   const int* __restrict__ batch,
                                                   const float* __restrict__ gattr,
                                                   const float* __restrict__ wf1,
                                                   const float* __restrict__ bf1,
                                                   const float* __restrict__ wf2,
                                                   const float* __restrict__ bf2,
                                                   float* __restrict__ out) {
  int g = blockIdx.x, tid = threadIdx.x;
  __shared__ float gv[HID + GA + 2];   // 262 + pad
  __shared__ float red[256];
  // count of nodes with batch==g: lower_bound(g+1) - lower_bound(g)
  auto lower_bound = [&](int key) {
    int lo = 0, hi = N_NODES;
    while (lo < hi) {
      int mid = (lo + hi) >> 1;
      if (batch[mid] < key) lo = mid + 1; else hi = mid;
    }
    return lo;
  };
  float c = (float)(lower_bound(g + 1) - lower_bound(g));
  c = fmaxf(c, 1.0f);
  gv[tid] = sums[(size_t)g * HID + tid] / c;
  if (tid < GA) gv[HID + tid] = gattr[g * GA + tid];
  if (tid < 2) gv[HID + GA + tid] = 0.f;
  __syncthreads();
  float ac0 = 0.f, ac1 = 0.f, ac2 = 0.f, ac3 = 0.f;
  float ac4 = 0.f, ac5 = 0.f, ac6 = 0.f, ac7 = 0.f;
  const float* wcol = wf1 + tid;
  int k = 0;
#pragma unroll 1
  for (; k + 8 <= HID + GA; k += 8) {
    float w0 = wcol[(size_t)(k + 0) * HID];
    float w1 = wcol[(size_t)(k + 1) * HID];
    float w2 = wcol[(size_t)(k + 2) * HID];
    float w3 = wcol[(size_t)(k + 3) * HID];
    float w4 = wcol[(size_t)(k + 4) * HID];
    float w5 = wcol[(size_t)(k + 5) * HID];
    float w6 = wcol[(size_t)(k + 6) * HID];
    float w7 = wcol[(size_t)(k + 7) * HID];
    ac0 = fmaf(gv[k + 0], w0, ac0);
    ac1 = fmaf(gv[k + 1], w1, ac1);
    ac2 = fmaf(gv[k + 2], w2, ac2);
    ac3 = fmaf(gv[k + 3], w3, ac3);
    ac4 = fmaf(gv[k + 4], w4, ac4);
    ac5 = fmaf(gv[k + 5], w5, ac5);
    ac6 = fmaf(gv[k + 6], w6, ac6);
    ac7 = fmaf(gv[k + 7], w7, ac7);
  }
  for (; k < HID + GA; k++)
    ac0 = fmaf(gv[k], wcol[(size_t)k * HID], ac0);
  float acc = ((ac0 + ac1) + (ac2 + ac3)) + ((ac4 + ac5) + (ac6 + ac7)) + bf1[tid];
  float h = fmaxf(acc, 0.f);
  red[tid] = h * wf2[tid];
  __syncthreads();
  for (int s = 128; s > 0; s >>= 1) {
    if (tid < s) red[tid] += red[tid + s];
    __syncthreads();
  }
  if (tid == 0) out[g] = red[0] + bf2[0];
}

// ---------------- launch ----------------

extern "C" void kernel_launch(void* const* d_in, const int* in_sizes, int n_in,
                              void* d_out, int out_size, void* d_ws, size_t ws_size,
                              hipStream_t stream) {
  const float* x     = (const float*)d_in[0];
  const int*   eidx  = (const int*)d_in[1];
  const int*   batch = (const int*)d_in[2];
  const float* gattr = (const float*)d_in[3];
  const float* w1a = (const float*)d_in[4];  const float* b1a = (const float*)d_in[5];
  const float* w1b = (const float*)d_in[6];  const float* b1b = (const float*)d_in[7];
  const float* w2a = (const float*)d_in[8];  const float* b2a = (const float*)d_in[9];
  const float* w2b = (const float*)d_in[10]; const float* b2b = (const float*)d_in[11];
  const float* wf1 = (const float*)d_in[12]; const float* bf1 = (const float*)d_in[13];
  const float* wf2 = (const float*)d_in[14]; const float* bf2 = (const float*)d_in[15];
  float* out = (float*)d_out;

  const int* esrc = eidx;
  const int* edst = eidx + N_EDGES;

  char* w = (char*)d_ws;
  auto alloc = [&](size_t bytes) -> void* {
    void* p = (void*)w;
    w += (bytes + 255) & ~(size_t)255;
    return p;
  };
  unsigned short* B0 = (unsigned short*)alloc((size_t)N_NODES * DIN * 2);  // x bf16
  unsigned short* B1 = (unsigned short*)alloc((size_t)N_NODES * HID * 2);  // agg out
  unsigned short* B2 = (unsigned short*)alloc((size_t)N_NODES * HID * 2);  // conv out
  unsigned short* B3 = (unsigned short*)alloc((size_t)N_NODES * HID * 2);  // h1
  unsigned short* w1aT = (unsigned short*)alloc(256 * 128 * 2);
  unsigned short* w1bT = (unsigned short*)alloc(256 * 256 * 2);
  unsigned short* w2aT = (unsigned short*)alloc(256 * 256 * 2);
  unsigned short* w2bT = (unsigned short*)alloc(256 * 256 * 2);
  int*   csr    = (int*)alloc((N_NODES + 4) * 4);
  int*   cursor = (int*)alloc(NBUCK * 4);
  unsigned int* tmp = (unsigned int*)alloc((size_t)NBUCK * BCAP * 4);
  int*   ssrc   = (int*)alloc((size_t)N_EDGES * 4);
  float* sums   = (float*)alloc((size_t)NGRAPH * HID * 4);

  hipMemsetAsync(cursor, 0, NBUCK * 4, stream);
  hipMemsetAsync(sums, 0, (size_t)NGRAPH * HID * 4, stream);

  cvt_all<<<12500 + 896, 256, 0, stream>>>(x, w1a, w1b, w2a, w2b,
                                           B0, w1aT, w1bT, w2aT, w2bT);

  bin_kernel<<<(N_EDGES + 4095) / 4096, 256, 0, stream>>>(esrc, edst, cursor, tmp);
  sort_kernel<<<NBUCK, 512, 0, stream>>>(tmp, cursor, csr, ssrc);

  const int ngemm = (N_NODES + 127) / 128;   // 782 blocks (full 256-col tiles)

  // conv1: agg(x) -> B1; relu(B1@W1a+b) -> B3; relu(B3@W1b+b) -> B2
  agg1_kernel<<<N_NODES / 4, 256, 0, stream>>>((const uint2*)B0, csr, ssrc, (uint2*)B1);
  gemm128<128, true, false><<<ngemm, 512, 0, stream>>>(B1, w1aT, b1a, B3, nullptr, nullptr);
  gemm128<256, true, false><<<ngemm, 512, 0, stream>>>(B3, w1bT, b1b, B2, nullptr, nullptr);
  // conv2: agg(B2) -> B1; relu(B1@W2a+b) -> B3; (B3@W2b+b) pooled into sums
  agg2_kernel<<<N_NODES / 4, 256, 0, stream>>>((const uint2*)B2, csr, ssrc, (uint2*)B1);
  gemm128<256, true, false><<<ngemm, 512, 0, stream>>>(B1, w2aT, b2a, B3, nullptr, nullptr);
  gemm128<256, false, true><<<ngemm, 512, 0, stream>>>(B3, w2bT, b2b, nullptr, batch, sums);

  head_kernel<<<NGRAPH, 256, 0, stream>>>(sums, batch, gattr, wf1, bf1, wf2, bf2, out);
}

// Round 16
// 388.518 us; speedup vs baseline: 2.4434x; 1.0389x over previous
//
#include <hip/hip_runtime.h>

#define N_NODES 100000
#define N_EDGES 1600000
#define NGRAPH  64
#define DIN     128
#define HID     256
#define GA      6

// bucketed CSR build
#define NBUCK  391       // ceil(100000 / 256)
#define BSHIFT 8         // 256 nodes per bucket
#define BCAP   6144      // per-bucket capacity (mean 4092, +32 sigma)
#define NCVT   13396     // 12500 x-blocks + 896 weight-blocks
#define NBIN   391       // ceil(1.6M / 4096)

typedef __attribute__((ext_vector_type(8))) short bf16x8;
typedef __attribute__((ext_vector_type(4))) float f32x4;

__device__ __forceinline__ unsigned short f2bf(float f) {
  unsigned int u = __float_as_uint(f);
  u += 0x7fffu + ((u >> 16) & 1u);
  return (unsigned short)(u >> 16);
}
__device__ __forceinline__ float bf_lo(unsigned int u) { return __uint_as_float(u << 16); }
__device__ __forceinline__ float bf_hi(unsigned int u) { return __uint_as_float(u & 0xffff0000u); }
__device__ __forceinline__ unsigned int packbf(float lo, float hi) {
  return (unsigned int)f2bf(lo) | ((unsigned int)f2bf(hi) << 16);
}

__device__ __forceinline__ void gload16(const void* g, void* l) {
  __builtin_amdgcn_global_load_lds(
      (const __attribute__((address_space(1))) unsigned int*)g,
      (__attribute__((address_space(3))) unsigned int*)l, 16, 0, 0);
}

// ---------------- fused: edge binning (blocks 0..390) + f32->bf16 conversions ----------------
// Independent work co-scheduled in one dispatch: bin blocks are atomic-latency
// bound, cvt blocks are BW bound — they overlap instead of serializing.

__global__ __launch_bounds__(256) void cvt_bin(const int* __restrict__ esrc,
                                               const int* __restrict__ edst,
                                               int* __restrict__ cursor,
                                               unsigned int* __restrict__ tmp,
                                               const float* __restrict__ x,
                                               const float* __restrict__ w1a,
                                               const float* __restrict__ w1b,
                                               const float* __restrict__ w2a,
                                               const float* __restrict__ w2b,
                                               unsigned short* __restrict__ xo,
                                               unsigned short* __restrict__ o1a,
                                               unsigned short* __restrict__ o1b,
                                               unsigned short* __restrict__ o2a,
                                               unsigned short* __restrict__ o2b) {
  __shared__ unsigned int pk[4096];
  __shared__ unsigned short bkb[4096];
  __shared__ int hist[NBUCK], lbase[NBUCK + 1], gbase[NBUCK], lcur[NBUCK];
  int bid = blockIdx.x, tid = threadIdx.x;

  if (bid >= NBIN) {
    // ---------------- cvt part ----------------
    bid -= NBIN;
    if (bid < 12500) {                     // x: 12.8M elems, 4/thread
      size_t idx = ((size_t)bid * 256 + tid) * 4;
      float4 v = *(const float4*)&x[idx];
      ushort4 o;
      o.x = f2bf(v.x); o.y = f2bf(v.y); o.z = f2bf(v.z); o.w = f2bf(v.w);
      *(ushort4*)&xo[idx] = o;
      return;
    }
    bid -= 12500;
    const float* in; unsigned short* out; int shift, idx;
    if (bid < 128)      { in = w1a; out = o1a; shift = 7; idx = bid * 256 + tid; }
    else if (bid < 384) { in = w1b; out = o1b; shift = 8; idx = (bid - 128) * 256 + tid; }
    else if (bid < 640) { in = w2a; out = o2a; shift = 8; idx = (bid - 384) * 256 + tid; }
    else                { in = w2b; out = o2b; shift = 8; idx = (bid - 640) * 256 + tid; }
    int K = 1 << shift;
    int n = idx >> shift;
    int k = idx & (K - 1);
    out[idx] = f2bf(in[(size_t)k * HID + n]);
    return;
  }

  // ---------------- bin part ----------------
  const int lane = tid & 63;
  const int ebase = bid * 4096;
  const int n = min(4096, N_EDGES - ebase);
  for (int i = tid; i < NBUCK; i += 256) hist[i] = 0;
  __syncthreads();
  unsigned int pkv[16]; int bk[16];
#pragma unroll
  for (int i = 0; i < 16; i++) {
    int e = ebase + i * 256 + tid;
    bk[i] = -1;
    if (e < N_EDGES) {
      int s = esrc[e], d = edst[e];
      bk[i] = d >> BSHIFT;
      pkv[i] = (unsigned int)s | ((unsigned int)(d & ((1 << BSHIFT) - 1)) << 17);
      atomicAdd(&hist[bk[i]], 1);
    }
  }
  __syncthreads();
  if (tid < 64) {                 // 8-per-lane exclusive scan of NBUCK counts
    int i0 = 8 * tid;
    int a[8], s = 0;
#pragma unroll
    for (int k = 0; k < 8; k++) {
      a[k] = (i0 + k < NBUCK) ? hist[i0 + k] : 0;
      s += a[k];
    }
    int sc = s;
#pragma unroll
    for (int off = 1; off < 64; off <<= 1) {
      int t = __shfl_up(sc, off);
      if (lane >= off) sc += t;
    }
    int excl = sc - s;
#pragma unroll
    for (int k = 0; k < 8; k++) {
      if (i0 + k < NBUCK) lbase[i0 + k] = excl;
      excl += a[k];
    }
    if (tid == 63) lbase[NBUCK] = sc;
  }
  __syncthreads();
  for (int i = tid; i < NBUCK; i += 256) {
    int c = hist[i];
    gbase[i] = c ? atomicAdd(&cursor[i], c) : 0;
    lcur[i] = lbase[i];
  }
  __syncthreads();
#pragma unroll
  for (int i = 0; i < 16; i++) {
    if (bk[i] >= 0) {
      int pos = atomicAdd(&lcur[bk[i]], 1);
      pk[pos] = pkv[i];
      bkb[pos] = (unsigned short)bk[i];
    }
  }
  __syncthreads();
#pragma unroll
  for (int i = 0; i < 16; i++) {
    int idx = i * 256 + tid;
    if (idx < n) {
      int b = bkb[idx];
      tmp[(size_t)b * BCAP + gbase[b] + (idx - lbase[b])] = pk[idx];
    }
  }
}

// ---------------- pass 2: per-bucket counting sort -> csr + ssrc ----------------

__global__ __launch_bounds__(512) void sort_kernel(const unsigned int* __restrict__ tmp,
                                                   const int* __restrict__ cnt,
                                                   int* __restrict__ csr,
                                                   int* __restrict__ ssrc) {
  __shared__ int nhist[256], ncur[256];
  __shared__ int bb[NBUCK];
  __shared__ int wsum[4];
  const int b = blockIdx.x;
  const int tid = threadIdx.x;
  const int lane = tid & 63, wid = tid >> 6;
  if (tid < 64) {                 // 8-per-lane scan of bucket counts -> edge bases
    int i0 = 8 * tid;
    int a[8], s = 0;
#pragma unroll
    for (int k = 0; k < 8; k++) {
      a[k] = (i0 + k < NBUCK) ? cnt[i0 + k] : 0;
      s += a[k];
    }
    int sc = s;
#pragma unroll
    for (int off = 1; off < 64; off <<= 1) {
      int t = __shfl_up(sc, off);
      if (lane >= off) sc += t;
    }
    int excl = sc - s;
#pragma unroll
    for (int k = 0; k < 8; k++) {
      if (i0 + k < NBUCK) bb[i0 + k] = excl;
      excl += a[k];
    }
  }
  if (tid < 256) nhist[tid] = 0;
  __syncthreads();
  const int myCnt = cnt[b];
  const int ebase = bb[b];
  const unsigned int* srcp = tmp + (size_t)b * BCAP;
  for (int i = tid; i < myCnt; i += 512)
    atomicAdd(&nhist[srcp[i] >> 17], 1);
  __syncthreads();
  // block scan of 256 node counts (1/thread, waves 0-3)
  int v = 0, sc = 0;
  if (tid < 256) {
    v = nhist[tid];
    sc = v;
#pragma unroll
    for (int off = 1; off < 64; off <<= 1) {
      int t = __shfl_up(sc, off);
      if (lane >= off) sc += t;
    }
    if (lane == 63) wsum[wid] = sc;
  }
  __syncthreads();
  if (tid < 4) {
    int ws = wsum[tid];
#pragma unroll
    for (int off = 1; off < 4; off <<= 1) {
      int t = __shfl_up(ws, off);
      if (tid >= off) ws += t;
    }
    wsum[tid] = ws;
  }
  __syncthreads();
  if (tid < 256) {
    int excl = ((wid > 0) ? wsum[wid - 1] : 0) + sc - v;
    ncur[tid] = excl;
    int node0 = (b << BSHIFT) + tid;
    if (node0 < N_NODES) csr[node0] = ebase + excl;
  }
  if (b == 0 && tid == 0) csr[N_NODES] = N_EDGES;
  __syncthreads();
  for (int i = tid; i < myCnt; i += 512) {
    unsigned int pe = srcp[i];
    int pos = atomicAdd(&ncur[pe >> 17], 1);
    ssrc[ebase + pos] = (int)(pe & 0x1FFFF);
  }
}

// ---------------- aggregation (bf16 in/out, f32 accum), deep-unrolled ----------------

__global__ __launch_bounds__(256) void agg1_kernel(const uint2* __restrict__ x,
                                                   const int* __restrict__ csr,
                                                   const int* __restrict__ ssrc,
                                                   uint2* __restrict__ out) {
  int node = blockIdx.x * 4 + (threadIdx.x >> 6);
  int lane = threadIdx.x & 63;
  int half = lane >> 5;        // which edge of each pair
  int dl   = lane & 31;        // dims dl*4 .. dl*4+3
  float a0 = 0.f, a1 = 0.f, a2 = 0.f, a3 = 0.f;
  if (half == 0) {             // self term once
    uint2 u = x[(size_t)node * 32 + dl];
    a0 = bf_lo(u.x); a1 = bf_hi(u.x); a2 = bf_lo(u.y); a3 = bf_hi(u.y);
  }
  int s = csr[node], e = csr[node + 1];
  int i = s;
  for (; i + 8 <= e; i += 8) {
    int s0 = ssrc[i + half],     s1 = ssrc[i + 2 + half];
    int s2 = ssrc[i + 4 + half], s3 = ssrc[i + 6 + half];
    uint2 v0 = x[(size_t)s0 * 32 + dl];
    uint2 v1 = x[(size_t)s1 * 32 + dl];
    uint2 v2 = x[(size_t)s2 * 32 + dl];
    uint2 v3 = x[(size_t)s3 * 32 + dl];
    a0 += bf_lo(v0.x) + bf_lo(v1.x) + bf_lo(v2.x) + bf_lo(v3.x);
    a1 += bf_hi(v0.x) + bf_hi(v1.x) + bf_hi(v2.x) + bf_hi(v3.x);
    a2 += bf_lo(v0.y) + bf_lo(v1.y) + bf_lo(v2.y) + bf_lo(v3.y);
    a3 += bf_hi(v0.y) + bf_hi(v1.y) + bf_hi(v2.y) + bf_hi(v3.y);
  }
  for (; i + 2 <= e; i += 2) {
    int sn = ssrc[i + half];
    uint2 v = x[(size_t)sn * 32 + dl];
    a0 += bf_lo(v.x); a1 += bf_hi(v.x);
    a2 += bf_lo(v.y); a3 += bf_hi(v.y);
  }
  if (i < e && half == 0) {    // odd tail
    uint2 v = x[(size_t)ssrc[i] * 32 + dl];
    a0 += bf_lo(v.x); a1 += bf_hi(v.x);
    a2 += bf_lo(v.y); a3 += bf_hi(v.y);
  }
  a0 += __shfl_xor(a0, 32);
  a1 += __shfl_xor(a1, 32);
  a2 += __shfl_xor(a2, 32);
  a3 += __shfl_xor(a3, 32);
  if (half == 0) {
    uint2 o;
    o.x = packbf(a0, a1);
    o.y = packbf(a2, a3);
    out[(size_t)node * 32 + dl] = o;
  }
}

__global__ __launch_bounds__(256) void agg2_kernel(const uint2* __restrict__ x,
                                                   const int* __restrict__ csr,
                                                   const int* __restrict__ ssrc,
                                                   uint2* __restrict__ out) {
  int node = blockIdx.x * 4 + (threadIdx.x >> 6);
  int lane = threadIdx.x & 63;
  uint2 u = x[(size_t)node * 64 + lane];
  float a0 = bf_lo(u.x), a1 = bf_hi(u.x), a2 = bf_lo(u.y), a3 = bf_hi(u.y);
  int s = csr[node], e = csr[node + 1];
  int i = s;
  for (; i + 8 <= e; i += 8) {
    int n0 = ssrc[i],     n1 = ssrc[i + 1], n2 = ssrc[i + 2], n3 = ssrc[i + 3];
    int n4 = ssrc[i + 4], n5 = ssrc[i + 5], n6 = ssrc[i + 6], n7 = ssrc[i + 7];
    uint2 v0 = x[(size_t)n0 * 64 + lane];
    uint2 v1 = x[(size_t)n1 * 64 + lane];
    uint2 v2 = x[(size_t)n2 * 64 + lane];
    uint2 v3 = x[(size_t)n3 * 64 + lane];
    uint2 v4 = x[(size_t)n4 * 64 + lane];
    uint2 v5 = x[(size_t)n5 * 64 + lane];
    uint2 v6 = x[(size_t)n6 * 64 + lane];
    uint2 v7 = x[(size_t)n7 * 64 + lane];
    a0 += (bf_lo(v0.x) + bf_lo(v1.x)) + (bf_lo(v2.x) + bf_lo(v3.x)) +
          (bf_lo(v4.x) + bf_lo(v5.x)) + (bf_lo(v6.x) + bf_lo(v7.x));
    a1 += (bf_hi(v0.x) + bf_hi(v1.x)) + (bf_hi(v2.x) + bf_hi(v3.x)) +
          (bf_hi(v4.x) + bf_hi(v5.x)) + (bf_hi(v6.x) + bf_hi(v7.x));
    a2 += (bf_lo(v0.y) + bf_lo(v1.y)) + (bf_lo(v2.y) + bf_lo(v3.y)) +
          (bf_lo(v4.y) + bf_lo(v5.y)) + (bf_lo(v6.y) + bf_lo(v7.y));
    a3 += (bf_hi(v0.y) + bf_hi(v1.y)) + (bf_hi(v2.y) + bf_hi(v3.y)) +
          (bf_hi(v4.y) + bf_hi(v5.y)) + (bf_hi(v6.y) + bf_hi(v7.y));
  }
  for (; i < e; i++) {
    uint2 v = x[(size_t)ssrc[i] * 64 + lane];
    a0 += bf_lo(v.x); a1 += bf_hi(v.x);
    a2 += bf_lo(v.y); a3 += bf_hi(v.y);
  }
  uint2 o;
  o.x = packbf(a0, a1);
  o.y = packbf(a2, a3);
  out[(size_t)node * 64 + lane] = o;
}

// ---------------- GEMM: 128 rows x 256 cols, 8 waves, BK=64 ----------------
// NO min-waves bound (r13 lesson: (512,6) spilled MFMA accumulators).

#define GMAX 4

template<int K, bool RELU, bool POOL>
__global__ __launch_bounds__(512)
void gemm128(const unsigned short* __restrict__ A,
             const unsigned short* __restrict__ Wt,
             const float* __restrict__ bias,
             unsigned short* __restrict__ C,
             const int* __restrict__ batch,
             float* __restrict__ sums) {
  __shared__ unsigned short Asl[128 * 64];   // 16 KB
  __shared__ unsigned short Wsl[256 * 64];   // 32 KB
  __shared__ float psum[POOL ? GMAX * HID : 1];  // 4 KB (POOL only)
  const int tid = threadIdx.x;
  const int lane = tid & 63;
  const int w = tid >> 6;          // 0..7
  const int wm = w >> 2;           // 0..1 (row half)
  const int wn = w & 3;            // 0..3 (col quarter)
  const int l15 = lane & 15, l4 = lane >> 4, l7 = lane & 7;
  const int rowBase = blockIdx.x * 128;

  if (POOL) {
#pragma unroll
    for (int i = tid; i < GMAX * HID; i += 512) psum[i] = 0.f;
  }

  f32x4 acc[4][4] = {};

  for (int k0 = 0; k0 < K; k0 += 64) {
#pragma unroll
    for (int i = 0; i < 2; i++) {            // stage A: 1024 chunks of 16B
      int c = i * 512 + tid;
      int m = c >> 3, koL = c & 7;
      int koS = koL ^ (m & 7);
      int gr = rowBase + m; if (gr >= N_NODES) gr = N_NODES - 1;
      gload16(&A[(size_t)gr * K + k0 + koS * 8], Asl + (size_t)c * 8);
    }
#pragma unroll
    for (int i = 0; i < 4; i++) {            // stage W: 2048 chunks of 16B
      int c = i * 512 + tid;
      int n = c >> 3, koL = c & 7;
      int koS = koL ^ (n & 7);
      gload16(&Wt[(size_t)n * K + k0 + koS * 8], Wsl + (size_t)c * 8);
    }
    __syncthreads();
#pragma unroll
    for (int kk = 0; kk < 2; kk++) {
      int koX = (kk * 4 + l4) ^ l7;
      bf16x8 a[4], b[4];
#pragma unroll
      for (int f = 0; f < 4; f++) {
        int rowA = wm * 64 + f * 16 + l15;
        int rowB = wn * 64 + f * 16 + l15;
        a[f] = *(const bf16x8*)&Asl[(size_t)(rowA * 64 + koX * 8)];
        b[f] = *(const bf16x8*)&Wsl[(size_t)(rowB * 64 + koX * 8)];
      }
#pragma unroll
      for (int fm = 0; fm < 4; fm++)
#pragma unroll
        for (int fn = 0; fn < 4; fn++)
          acc[fm][fn] = __builtin_amdgcn_mfma_f32_16x16x32_bf16(a[fm], b[fn], acc[fm][fn], 0, 0, 0);
    }
    __syncthreads();
  }

  if (!POOL) {
#pragma unroll
    for (int fm = 0; fm < 4; fm++) {
      int r0 = rowBase + wm * 64 + fm * 16 + l4 * 4;
#pragma unroll
      for (int fn = 0; fn < 4; fn++) {
        int col = wn * 64 + fn * 16 + l15;
        float bb = bias[col];
#pragma unroll
        for (int j = 0; j < 4; j++) {
          int r = r0 + j;
          if (r < N_NODES) {
            float v = acc[fm][fn][j] + bb;
            if (RELU) v = fmaxf(v, 0.f);
            C[(size_t)r * HID + col] = f2bf(v);
          }
        }
      }
    }
  } else {
    // fused mean-pool epilogue: accumulate f32 per-graph partials
    const int g0 = batch[rowBase];
#pragma unroll
    for (int fn = 0; fn < 4; fn++) {
      int col = wn * 64 + fn * 16 + l15;
      float bb = bias[col];
      float part = 0.f;
      int curgi = -1;
#pragma unroll
      for (int fm = 0; fm < 4; fm++) {
#pragma unroll
        for (int j = 0; j < 4; j++) {
          int r = rowBase + wm * 64 + fm * 16 + l4 * 4 + j;
          if (r < N_NODES) {
            float v = acc[fm][fn][j] + bb;
            int gi = batch[r] - g0;
            if (gi != curgi) {
              if (curgi >= 0) {
                if (curgi < GMAX) atomicAdd(&psum[curgi * HID + col], part);
                else atomicAdd(&sums[(size_t)(g0 + curgi) * HID + col], part);
              }
              curgi = gi; part = 0.f;
            }
            part += v;
          }
        }
      }
      if (curgi >= 0) {
        if (curgi < GMAX) atomicAdd(&psum[curgi * HID + col], part);
        else atomicAdd(&sums[(size_t)(g0 + curgi) * HID + col], part);
      }
    }
    __syncthreads();
#pragma unroll
    for (int i = tid; i < GMAX * HID; i += 512) {
      float v = psum[i];
      int g = g0 + (i >> 8);
      if (v != 0.f && g < NGRAPH)
        atomicAdd(&sums[(size_t)g * HID + (i & 255)], v);
    }
  }
}

// ---------------- head: mean + relu(g@wf1+bf1)@wf2+bf2; counts via binary search ----------------

__global__ __launch_bounds__(256) void head_kernel(const float* __restrict__ sums,
                                                   const int* __restrict__ batch,
                                                   const float* __restrict__ gattr,
                                                   const float* __restrict__ wf1,
                                                   const float* __restrict__ bf1,
                                                   const float* __restrict__ wf2,
                                                   const float* __restrict__ bf2,
                                                   float* __restrict__ out) {
  int g = blockIdx.x, tid = threadIdx.x;
  __shared__ float gv[HID + GA + 2];   // 262 + pad
  __shared__ float red[256];
  auto lower_bound = [&](int key) {
    int lo = 0, hi = N_NODES;
    while (lo < hi) {
      int mid = (lo + hi) >> 1;
      if (batch[mid] < key) lo = mid + 1; else hi = mid;
    }
    return lo;
  };
  float c = (float)(lower_bound(g + 1) - lower_bound(g));
  c = fmaxf(c, 1.0f);
  gv[tid] = sums[(size_t)g * HID + tid] / c;
  if (tid < GA) gv[HID + tid] = gattr[g * GA + tid];
  if (tid < 2) gv[HID + GA + tid] = 0.f;
  __syncthreads();
  float ac0 = 0.f, ac1 = 0.f, ac2 = 0.f, ac3 = 0.f;
  float ac4 = 0.f, ac5 = 0.f, ac6 = 0.f, ac7 = 0.f;
  const float* wcol = wf1 + tid;
  int k = 0;
#pragma unroll 1
  for (; k + 8 <= HID + GA; k += 8) {
    float w0 = wcol[(size_t)(k + 0) * HID];
    float w1 = wcol[(size_t)(k + 1) * HID];
    float w2 = wcol[(size_t)(k + 2) * HID];
    float w3 = wcol[(size_t)(k + 3) * HID];
    float w4 = wcol[(size_t)(k + 4) * HID];
    float w5 = wcol[(size_t)(k + 5) * HID];
    float w6 = wcol[(size_t)(k + 6) * HID];
    float w7 = wcol[(size_t)(k + 7) * HID];
    ac0 = fmaf(gv[k + 0], w0, ac0);
    ac1 = fmaf(gv[k + 1], w1, ac1);
    ac2 = fmaf(gv[k + 2], w2, ac2);
    ac3 = fmaf(gv[k + 3], w3, ac3);
    ac4 = fmaf(gv[k + 4], w4, ac4);
    ac5 = fmaf(gv[k + 5], w5, ac5);
    ac6 = fmaf(gv[k + 6], w6, ac6);
    ac7 = fmaf(gv[k + 7], w7, ac7);
  }
  for (; k < HID + GA; k++)
    ac0 = fmaf(gv[k], wcol[(size_t)k * HID], ac0);
  float acc = ((ac0 + ac1) + (ac2 + ac3)) + ((ac4 + ac5) + (ac6 + ac7)) + bf1[tid];
  float h = fmaxf(acc, 0.f);
  red[tid] = h * wf2[tid];
  __syncthreads();
  for (int s = 128; s > 0; s >>= 1) {
    if (tid < s) red[tid] += red[tid + s];
    __syncthreads();
  }
  if (tid == 0) out[g] = red[0] + bf2[0];
}

// ---------------- launch ----------------

extern "C" void kernel_launch(void* const* d_in, const int* in_sizes, int n_in,
                              void* d_out, int out_size, void* d_ws, size_t ws_size,
                              hipStream_t stream) {
  const float* x     = (const float*)d_in[0];
  const int*   eidx  = (const int*)d_in[1];
  const int*   batch = (const int*)d_in[2];
  const float* gattr = (const float*)d_in[3];
  const float* w1a = (const float*)d_in[4];  const float* b1a = (const float*)d_in[5];
  const float* w1b = (const float*)d_in[6];  const float* b1b = (const float*)d_in[7];
  const float* w2a = (const float*)d_in[8];  const float* b2a = (const float*)d_in[9];
  const float* w2b = (const float*)d_in[10]; const float* b2b = (const float*)d_in[11];
  const float* wf1 = (const float*)d_in[12]; const float* bf1 = (const float*)d_in[13];
  const float* wf2 = (const float*)d_in[14]; const float* bf2 = (const float*)d_in[15];
  float* out = (float*)d_out;

  const int* esrc = eidx;
  const int* edst = eidx + N_EDGES;

  char* w = (char*)d_ws;
  auto alloc = [&](size_t bytes) -> void* {
    void* p = (void*)w;
    w += (bytes + 255) & ~(size_t)255;
    return p;
  };
  unsigned short* B0 = (unsigned short*)alloc((size_t)N_NODES * DIN * 2);  // x bf16
  unsigned short* B1 = (unsigned short*)alloc((size_t)N_NODES * HID * 2);  // agg out
  unsigned short* B2 = (unsigned short*)alloc((size_t)N_NODES * HID * 2);  // conv out
  unsigned short* B3 = (unsigned short*)alloc((size_t)N_NODES * HID * 2);  // h1
  unsigned short* w1aT = (unsigned short*)alloc(256 * 128 * 2);
  unsigned short* w1bT = (unsigned short*)alloc(256 * 256 * 2);
  unsigned short* w2aT = (unsigned short*)alloc(256 * 256 * 2);
  unsigned short* w2bT = (unsigned short*)alloc(256 * 256 * 2);
  int*   csr    = (int*)alloc((N_NODES + 4) * 4);
  // cursor + sums adjacent -> single memset
  int*   cursor = (int*)alloc(NBUCK * 4);                  // 1564 -> 1792 rounded
  float* sums   = (float*)alloc((size_t)NGRAPH * HID * 4); // 64 KB
  unsigned int* tmp = (unsigned int*)alloc((size_t)NBUCK * BCAP * 4);
  int*   ssrc   = (int*)alloc((size_t)N_EDGES * 4);

  size_t zbytes = ((NBUCK * 4 + 255) & ~(size_t)255) + (size_t)NGRAPH * HID * 4;
  hipMemsetAsync(cursor, 0, zbytes, stream);

  cvt_bin<<<NBIN + NCVT, 256, 0, stream>>>(esrc, edst, cursor, tmp,
                                           x, w1a, w1b, w2a, w2b,
                                           B0, w1aT, w1bT, w2aT, w2bT);
  sort_kernel<<<NBUCK, 512, 0, stream>>>(tmp, cursor, csr, ssrc);

  const int ngemm = (N_NODES + 127) / 128;   // 782 blocks (full 256-col tiles)

  // conv1: agg(x) -> B1; relu(B1@W1a+b) -> B3; relu(B3@W1b+b) -> B2
  agg1_kernel<<<N_NODES / 4, 256, 0, stream>>>((const uint2*)B0, csr, ssrc, (uint2*)B1);
  gemm128<128, true, false><<<ngemm, 512, 0, stream>>>(B1, w1aT, b1a, B3, nullptr, nullptr);
  gemm128<256, true, false><<<ngemm, 512, 0, stream>>>(B3, w1bT, b1b, B2, nullptr, nullptr);
  // conv2: agg(B2) -> B1; relu(B1@W2a+b) -> B3; (B3@W2b+b) pooled into sums
  agg2_kernel<<<N_NODES / 4, 256, 0, stream>>>((const uint2*)B2, csr, ssrc, (uint2*)B1);
  gemm128<256, true, false><<<ngemm, 512, 0, stream>>>(B1, w2aT, b2a, B3, nullptr, nullptr);
  gemm128<256, false, true><<<ngemm, 512, 0, stream>>>(B3, w2bT, b2b, nullptr, batch, sums);

  head_kernel<<<NGRAPH, 256, 0, stream>>>(sums, batch, gattr, wf1, bf1, wf2, bf2, out);
}